// Round 2
// baseline (5470.336 us; speedup 1.0000x reference)
//
#include <hip/hip_runtime.h>
#include <hip/hip_bf16.h>

#define B_  1024
#define T_  128
#define V_  89
#define H_  256
#define H3_ 768
#define V2_ 178
#define BT_ (B_*T_)
#define NBLK1 356     // B_*V_ / 256 == 91136/256

__device__ __forceinline__ float bf2f(__hip_bfloat16 v){ return __bfloat162float(v); }
__device__ __forceinline__ __hip_bfloat16 f2bf(float v){ return __float2bfloat16(v); }
__device__ __forceinline__ float sigmoidf_(float x){ return 1.f/(1.f+expf(-x)); }

// ---------------------------------------------------------------- K1: imputation
// one thread per (b,v); loops T. Writes x_imp and per-(t,block) loss partials.
__global__ __launch_bounds__(256) void k_impute(
    const float* __restrict__ x, const float* __restrict__ mask,
    const float* __restrict__ deltas, const float* __restrict__ meanset,
    const float* __restrict__ W_x, const float* __restrict__ b_x,
    float* __restrict__ ximp, float* __restrict__ num_part, float* __restrict__ den_part)
{
    int tid = threadIdx.x;
    int i = blockIdx.x*256 + tid;             // < 91136 exactly
    int b = i / V_, v = i - b*V_;
    float wxd = W_x[v*V_ + v];
    float bx  = b_x[v];
    float mv  = meanset[v];
    const float* xp = x      + (size_t)b*T_*V_ + v;
    const float* mp = mask   + (size_t)b*T_*V_ + v;
    const float* dp = deltas + (size_t)b*T_*V_ + v;
    float*       op = ximp   + (size_t)b*T_*V_ + v;
    float last = 0.f;
    __shared__ float s_n[4], s_d[4];
    int lane = tid & 63, wid = tid >> 6;
    for (int t = 0; t < T_; ++t) {
        float xt = xp[t*V_], m = mp[t*V_], d = dp[t*V_];
        float g = expf(-fmaxf(fmaf(d, wxd, bx), 0.f));
        last = (m > 0.f) ? xt : last;
        float xu = g*last + (1.f-g)*mv;
        op[t*V_] = m*xt + (1.f-m)*xu;
        float nv = fabsf(xt - xu)*m;
        float dv = m;
        for (int off = 32; off; off >>= 1) {
            nv += __shfl_down(nv, off);
            dv += __shfl_down(dv, off);
        }
        if (lane == 0) { s_n[wid] = nv; s_d[wid] = dv; }
        __syncthreads();
        if (tid == 0) {
            num_part[t*NBLK1 + blockIdx.x] = s_n[0]+s_n[1]+s_n[2]+s_n[3];
            den_part[t*NBLK1 + blockIdx.x] = s_d[0]+s_d[1]+s_d[2]+s_d[3];
        }
        __syncthreads();
    }
}

// ---------------------------------------------------------------- K2: loss finalize
__global__ __launch_bounds__(128) void k_loss(
    const float* __restrict__ num_part, const float* __restrict__ den_part,
    float* __restrict__ out_loss)
{
    int t = threadIdx.x; // 0..127
    float num = 0.f, den = 0.f;
    for (int j = 0; j < NBLK1; ++j) { num += num_part[t*NBLK1+j]; den += den_part[t*NBLK1+j]; }
    float s = num / (den + 1e-5f);
    for (int off = 32; off; off >>= 1) s += __shfl_down(s, off);
    __shared__ float sp[2];
    if ((t&63)==0) sp[t>>6] = s;
    __syncthreads();
    if (t==0) out_loss[0] = sp[0] + sp[1];
}

// ---------------------------------------------------------------- K: fp32->bf16 convert
__global__ __launch_bounds__(256) void k_cvt(const float* __restrict__ w,
                                             __hip_bfloat16* __restrict__ o, int n){
    int i = blockIdx.x*256 + threadIdx.x;
    if (i < n) o[i] = f2bf(w[i]);
}

// ---------------------------------------------------------------- K3: gamma_h GEMM (chunk)
// rows r in [0, B*TC); b = r>>tcShift, lt = r&(TC-1); global t = t0+lt. fp32 out.
__global__ __launch_bounds__(256) void k_gammah(
    const float* __restrict__ deltas, const float* __restrict__ W_h,
    const float* __restrict__ b_h, float* __restrict__ gH,
    int t0, int tcShift)
{
    __shared__ float dl[16][90];
    int r0 = blockIdx.x * 16;
    int tid = threadIdx.x;
    int tcm = (1<<tcShift) - 1;
    for (int idx = tid; idx < 16*V_; idx += 256) {
        int r = idx / V_, k = idx - r*V_;
        int rr = r0 + r;
        int b = rr >> tcShift, lt = rr & tcm;
        dl[r][k] = deltas[((size_t)b*T_ + t0 + lt)*V_ + k];
    }
    __syncthreads();
    float acc[16];
    #pragma unroll
    for (int r = 0; r < 16; ++r) acc[r] = 0.f;
    int c = tid;
    const float* wp = W_h + (size_t)c*V_;
    for (int k = 0; k < V_; ++k) {
        float w = wp[k];
        #pragma unroll
        for (int r = 0; r < 16; ++r) acc[r] = fmaf(dl[r][k], w, acc[r]);
    }
    float bh = b_h[c];
    #pragma unroll
    for (int r = 0; r < 16; ++r)
        gH[(size_t)(r0+r)*H_ + c] = expf(-fmaxf(acc[r]+bh, 0.f));
}

// ---------------------------------------------------------------- K4: gi GEMM (chunk)
// [B*TC,178] @ [178,768] + b_ih, fp32 out. 16 rows x 256 cols per block.
__global__ __launch_bounds__(256) void k_gi(
    const float* __restrict__ ximp, const float* __restrict__ mask,
    const float* __restrict__ W_ih, const float* __restrict__ b_ih,
    float* __restrict__ gi, int t0, int tcShift)
{
    __shared__ float cl[16][180];
    int r0 = blockIdx.x * 16;
    int c0 = blockIdx.y * 256;
    int tid = threadIdx.x;
    int tcm = (1<<tcShift) - 1;
    for (int idx = tid; idx < 16*V2_; idx += 256) {
        int r = idx / V2_, k = idx - r*V2_;
        int rr = r0 + r;
        int b = rr >> tcShift, lt = rr & tcm;
        size_t base = ((size_t)b*T_ + t0 + lt)*V_;
        cl[r][k] = (k < V_) ? ximp[base + k] : mask[base + (k - V_)];
    }
    __syncthreads();
    int c = c0 + tid;
    float acc[16];
    #pragma unroll
    for (int r = 0; r < 16; ++r) acc[r] = 0.f;
    const float* wp = W_ih + (size_t)c*V2_;
    for (int k = 0; k < V2_; ++k) {
        float w = wp[k];
        #pragma unroll
        for (int r = 0; r < 16; ++r) acc[r] = fmaf(cl[r][k], w, acc[r]);
    }
    float bi = b_ih[c];
    #pragma unroll
    for (int r = 0; r < 16; ++r)
        gi[(size_t)(r0+r)*H3_ + c] = acc[r] + bi;
}

// ---------------------------------------------------------------- K5: GRU recurrence (chunk)
// 256 blocks x 256 thr; block owns 4 batch rows; h carried via hstate.
__global__ __launch_bounds__(256) void k_recur(
    const float* __restrict__ gi, const float* __restrict__ gH,
    const __hip_bfloat16* __restrict__ whh, const float* __restrict__ b_hh,
    const float* __restrict__ W_cls, const float* __restrict__ b_cls,
    float* __restrict__ hstate, float* __restrict__ yout, float* __restrict__ yscore,
    int TC, int first, int last)
{
    __shared__ float hd[4][258];   // decayed h; row stride even -> 8B-aligned float2 reads
    int tid = threadIdx.x;
    int b0 = blockIdx.x * 4;
    float h[4];
    #pragma unroll
    for (int r = 0; r < 4; ++r)
        h[r] = first ? 0.f : hstate[(size_t)(b0+r)*H_ + tid];
    float bhr = b_hh[tid], bhz = b_hh[tid+H_], bhn = b_hh[tid+2*H_];
    const __hip_bfloat162* w2 = (const __hip_bfloat162*)whh;
    for (int lt = 0; lt < TC; ++lt) {
        float hdec[4];
        #pragma unroll
        for (int r = 0; r < 4; ++r)
            hdec[r] = h[r] * gH[((size_t)(b0+r)*TC + lt)*H_ + tid];
        __syncthreads();           // prior step's GEMM reads complete
        #pragma unroll
        for (int r = 0; r < 4; ++r) hd[r][tid] = hdec[r];
        __syncthreads();           // hd published
        float ar[4], az[4], an[4];
        #pragma unroll
        for (int r = 0; r < 4; ++r){ ar[r]=bhr; az[r]=bhz; an[r]=bhn; }
        const __hip_bfloat162* wr = w2 + (size_t)tid*128;
        const __hip_bfloat162* wz = w2 + (size_t)(tid+H_)*128;
        const __hip_bfloat162* wn = w2 + (size_t)(tid+2*H_)*128;
        for (int kk = 0; kk < 128; ++kk) {
            float2 fr = __bfloat1622float2(wr[kk]);
            float2 fz = __bfloat1622float2(wz[kk]);
            float2 fn = __bfloat1622float2(wn[kk]);
            #pragma unroll
            for (int r = 0; r < 4; ++r) {
                float2 h2 = *(const float2*)&hd[r][2*kk];
                ar[r] = fmaf(h2.x, fr.x, fmaf(h2.y, fr.y, ar[r]));
                az[r] = fmaf(h2.x, fz.x, fmaf(h2.y, fz.y, az[r]));
                an[r] = fmaf(h2.x, fn.x, fmaf(h2.y, fn.y, an[r]));
            }
        }
        #pragma unroll
        for (int r = 0; r < 4; ++r) {
            size_t gidx = ((size_t)(b0+r)*TC + lt)*H3_ + tid;
            float ir  = gi[gidx];
            float iz  = gi[gidx+H_];
            float in_ = gi[gidx+2*H_];
            float rg = sigmoidf_(ir + ar[r]);
            float zg = sigmoidf_(iz + az[r]);
            float ng = tanhf(in_ + rg*an[r]);
            h[r] = (1.f-zg)*ng + zg*hdec[r];
        }
    }
    #pragma unroll
    for (int r = 0; r < 4; ++r) hstate[(size_t)(b0+r)*H_ + tid] = h[r];
    if (last) {
        float wc = W_cls[tid];
        __shared__ float yp[4][4];
        int lane = tid & 63, wid = tid >> 6;
        #pragma unroll
        for (int r = 0; r < 4; ++r) {
            float v = h[r]*wc;
            for (int off = 32; off; off >>= 1) v += __shfl_down(v, off);
            if (lane == 0) yp[r][wid] = v;
        }
        __syncthreads();
        if (tid < 4) {
            float s = yp[tid][0]+yp[tid][1]+yp[tid][2]+yp[tid][3] + b_cls[0];
            yout[b0+tid]   = s;
            yscore[b0+tid] = 1.f/(1.f+expf(-s));
        }
    }
}

static inline size_t align256(size_t x){ return (x + 255) & ~(size_t)255; }

extern "C" void kernel_launch(void* const* d_in, const int* in_sizes, int n_in,
                              void* d_out, int out_size, void* d_ws, size_t ws_size,
                              hipStream_t stream)
{
    const float* x      = (const float*)d_in[0];
    const float* mask   = (const float*)d_in[1];
    const float* deltas = (const float*)d_in[2];
    const float* meanset= (const float*)d_in[3];
    const float* W_h    = (const float*)d_in[4];
    const float* b_h    = (const float*)d_in[5];
    const float* W_x    = (const float*)d_in[6];
    const float* b_x    = (const float*)d_in[7];
    const float* W_ih   = (const float*)d_in[8];
    const float* b_ih   = (const float*)d_in[9];
    const float* W_hh   = (const float*)d_in[10];
    const float* b_hh   = (const float*)d_in[11];
    const float* W_cls  = (const float*)d_in[12];
    const float* b_cls  = (const float*)d_in[13];

    float* out    = (float*)d_out;
    float* ximp   = out;                        // B*T*V
    float* xloss  = out + (size_t)B_*T_*V_;     // 1
    float* yout   = xloss + 1;                  // B
    float* yscore = yout + B_;                  // B

    // pick largest power-of-2 chunk TC such that the workspace fits ws_size
    int tcShift = -1;
    size_t off_gi=0, off_gH=0, off_whh=0, off_h=0, off_np=0, off_dp=0;
    for (int s = 7; s >= 0; --s) {
        size_t TC = (size_t)1 << s;
        size_t o = 0;
        size_t gi_b  = (size_t)B_*TC*H3_*4;  off_gi  = o; o = align256(o + gi_b);
        size_t gH_b  = (size_t)B_*TC*H_*4;   off_gH  = o; o = align256(o + gH_b);
        size_t whh_b = (size_t)H3_*H_*2;     off_whh = o; o = align256(o + whh_b);
        size_t h_b   = (size_t)B_*H_*4;      off_h   = o; o = align256(o + h_b);
        size_t np_b  = (size_t)T_*NBLK1*4;   off_np  = o; o = align256(o + np_b);
                                             off_dp  = o; o = align256(o + np_b);
        if (o <= ws_size) { tcShift = s; break; }
    }
    if (tcShift < 0) return;  // workspace too small for even TC=1
    int TC = 1 << tcShift;
    int NC = T_ / TC;

    char* ws = (char*)d_ws;
    float* gi             = (float*)(ws + off_gi);
    float* gH             = (float*)(ws + off_gH);
    __hip_bfloat16* whhb  = (__hip_bfloat16*)(ws + off_whh);
    float* hstate         = (float*)(ws + off_h);
    float* numpart        = (float*)(ws + off_np);
    float* denpart        = (float*)(ws + off_dp);

    hipLaunchKernelGGL(k_cvt, dim3((H3_*H_+255)/256), dim3(256), 0, stream,
                       W_hh, whhb, H3_*H_);
    hipLaunchKernelGGL(k_impute, dim3(NBLK1), dim3(256), 0, stream,
                       x, mask, deltas, meanset, W_x, b_x, ximp, numpart, denpart);
    hipLaunchKernelGGL(k_loss, dim3(1), dim3(128), 0, stream, numpart, denpart, xloss);

    for (int c = 0; c < NC; ++c) {
        int t0 = c * TC;
        hipLaunchKernelGGL(k_gammah, dim3(B_*TC/16), dim3(256), 0, stream,
                           deltas, W_h, b_h, gH, t0, tcShift);
        hipLaunchKernelGGL(k_gi, dim3(B_*TC/16, 3), dim3(256), 0, stream,
                           ximp, mask, W_ih, b_ih, gi, t0, tcShift);
        hipLaunchKernelGGL(k_recur, dim3(B_/4), dim3(256), 0, stream,
                           gi, gH, whhb, b_hh, W_cls, b_cls,
                           hstate, yout, yscore, TC, c==0, c==NC-1);
    }
}

// Round 3
// 1933.906 us; speedup vs baseline: 2.8286x; 2.8286x over previous
//
#include <hip/hip_runtime.h>

#define B_  1024
#define T_  128
#define V_  89
#define H_  256
#define H3_ 768
#define V2_ 178
#define BT_ (B_*T_)
#define NBLK1 356            // B_*V_ / 256
#define NW1   (NBLK1*4)      // wave partials

typedef __attribute__((ext_vector_type(8))) short bf16x8;
typedef __attribute__((ext_vector_type(4))) float f32x4;

__device__ __forceinline__ short f2bs(float f){
    unsigned u = __float_as_uint(f);
    unsigned r = (u + 0x7FFFu + ((u>>16)&1u)) >> 16;
    return (short)r;
}
__device__ __forceinline__ float s2f(short s){
    return __uint_as_float(((unsigned)(unsigned short)s) << 16);
}
__device__ __forceinline__ float sig_(float x){ return 1.f/(1.f+__expf(-x)); }
__device__ __forceinline__ float tanh_(float x){ return 2.f/(1.f+__expf(-2.f*x)) - 1.f; }

// ---------------------------------------------------------------- pad+convert fp32 -> bf16
__global__ __launch_bounds__(256) void k_pad_cvt(
    const float* __restrict__ src, short* __restrict__ dst, int R, int C, int Cp)
{
    int i = blockIdx.x*256 + threadIdx.x;
    if (i >= R*Cp) return;
    int r = i / Cp, k = i - r*Cp;
    dst[i] = (k < C) ? f2bs(src[r*C + k]) : (short)0;
}

// ---------------------------------------------------------------- K1: imputation (no barriers)
__global__ __launch_bounds__(256) void k_impute(
    const float* __restrict__ x, const float* __restrict__ mask,
    const float* __restrict__ deltas, const float* __restrict__ meanset,
    const float* __restrict__ W_x, const float* __restrict__ b_x,
    float* __restrict__ ximp, float* __restrict__ num_part, float* __restrict__ den_part)
{
    int tid = threadIdx.x;
    int i = blockIdx.x*256 + tid;             // < 91136 exactly
    int b = i / V_, v = i - b*V_;
    float wxd = W_x[v*V_ + v];
    float bx  = b_x[v];
    float mv  = meanset[v];
    const float* xp = x      + (size_t)b*T_*V_ + v;
    const float* mp = mask   + (size_t)b*T_*V_ + v;
    const float* dp = deltas + (size_t)b*T_*V_ + v;
    float*       op = ximp   + (size_t)b*T_*V_ + v;
    float last = 0.f;
    int lane = tid & 63, wid = tid >> 6;
    int gw = blockIdx.x*4 + wid;
    for (int t = 0; t < T_; ++t) {
        float xt = xp[t*V_], m = mp[t*V_], d = dp[t*V_];
        float g = __expf(-fmaxf(fmaf(d, wxd, bx), 0.f));
        last = (m > 0.f) ? xt : last;
        float xu = g*last + (1.f-g)*mv;
        op[t*V_] = m*xt + (1.f-m)*xu;
        float nv = fabsf(xt - xu)*m;
        float dv = m;
        for (int off = 32; off; off >>= 1) {
            nv += __shfl_down(nv, off);
            dv += __shfl_down(dv, off);
        }
        if (lane == 0) { num_part[t*NW1 + gw] = nv; den_part[t*NW1 + gw] = dv; }
    }
}

// ---------------------------------------------------------------- loss stage 1: per-t sum
__global__ __launch_bounds__(256) void k_loss_t(
    const float* __restrict__ num_part, const float* __restrict__ den_part,
    float* __restrict__ tpart)
{
    int t = blockIdx.x, tid = threadIdx.x;
    float num = 0.f, den = 0.f;
    for (int j = tid; j < NW1; j += 256) { num += num_part[t*NW1+j]; den += den_part[t*NW1+j]; }
    for (int off = 32; off; off >>= 1) { num += __shfl_down(num, off); den += __shfl_down(den, off); }
    __shared__ float sn[4], sd[4];
    int lane = tid & 63, wid = tid >> 6;
    if (lane == 0) { sn[wid] = num; sd[wid] = den; }
    __syncthreads();
    if (tid == 0) {
        float n = sn[0]+sn[1]+sn[2]+sn[3], d = sd[0]+sd[1]+sd[2]+sd[3];
        tpart[t] = n / (d + 1e-5f);
    }
}

// ---------------------------------------------------------------- loss stage 2: sum over t
__global__ __launch_bounds__(128) void k_loss_final(
    const float* __restrict__ tpart, float* __restrict__ out_loss)
{
    int tid = threadIdx.x;
    float s = tpart[tid];
    for (int off = 32; off; off >>= 1) s += __shfl_down(s, off);
    __shared__ float sp[2];
    if ((tid&63)==0) sp[tid>>6] = s;
    __syncthreads();
    if (tid==0) out_loss[0] = sp[0] + sp[1];
}

// ---------------------------------------------------------------- K4: gi GEMM via MFMA
// rows = B*TC; block = 32 rows; 4 waves x 192 cols. K padded 178->192.
__global__ __launch_bounds__(256) void k_gi(
    const float* __restrict__ ximp, const float* __restrict__ mask,
    const short* __restrict__ whib, const float* __restrict__ b_ih,
    short* __restrict__ gi, int t0, int tcShift)
{
    __shared__ short xl[32*200];
    int tid = threadIdx.x;
    int r0 = blockIdx.x * 32;
    int tcm = (1<<tcShift) - 1;
    // stage X2 = [ximp | mask] as bf16, k-padded to 192
    for (int i = tid; i < 32*192; i += 256) {
        int r = i / 192, k = i - (i/192)*192;
        int R = r0 + r;
        int b = R >> tcShift, lt = R & tcm;
        size_t base = ((size_t)b*T_ + t0 + lt)*V_;
        float val = 0.f;
        if (k < V_)        val = ximp[base + k];
        else if (k < V2_)  val = mask[base + (k - V_)];
        xl[r*200 + k] = f2bs(val);
    }
    __syncthreads();
    int lane = tid & 63, w = tid >> 6;
    int l15 = lane & 15, g8 = lane >> 4;
    f32x4 acc[2][12];
    f32x4 z4 = {0.f,0.f,0.f,0.f};
    #pragma unroll
    for (int mt = 0; mt < 2; ++mt)
        #pragma unroll
        for (int nt = 0; nt < 12; ++nt) acc[mt][nt] = z4;
    #pragma unroll
    for (int kt = 0; kt < 6; ++kt) {
        bf16x8 a0 = *(const bf16x8*)&xl[(l15     )*200 + kt*32 + g8*8];
        bf16x8 a1 = *(const bf16x8*)&xl[(16 + l15)*200 + kt*32 + g8*8];
        #pragma unroll
        for (int nt = 0; nt < 12; ++nt) {
            int n = w*192 + nt*16 + l15;
            bf16x8 bb = *(const bf16x8*)(whib + (size_t)n*192 + kt*32 + g8*8);
            acc[0][nt] = __builtin_amdgcn_mfma_f32_16x16x32_bf16(a0, bb, acc[0][nt], 0,0,0);
            acc[1][nt] = __builtin_amdgcn_mfma_f32_16x16x32_bf16(a1, bb, acc[1][nt], 0,0,0);
        }
    }
    float bias[12];
    #pragma unroll
    for (int nt = 0; nt < 12; ++nt) bias[nt] = b_ih[w*192 + nt*16 + l15];
    #pragma unroll
    for (int mt = 0; mt < 2; ++mt)
        #pragma unroll
        for (int nt = 0; nt < 12; ++nt)
            #pragma unroll
            for (int rr = 0; rr < 4; ++rr) {
                int row = r0 + mt*16 + g8*4 + rr;
                int col = w*192 + nt*16 + l15;
                gi[(size_t)row*H3_ + col] = f2bs(acc[mt][nt][rr] + bias[nt]);
            }
}

// ---------------------------------------------------------------- K5: GRU recurrence via MFMA
// 64 blocks x 512 thr (8 waves). MB=16 rows/block. Wave w owns h-cols [w*32, w*32+32).
__global__ __launch_bounds__(512, 2) void k_recur(
    const short* __restrict__ gi, const short* __restrict__ whhb,
    const short* __restrict__ whp, const float* __restrict__ deltas,
    const float* __restrict__ b_h, const float* __restrict__ b_hh,
    const float* __restrict__ W_cls, const float* __restrict__ b_cls,
    float* __restrict__ hstate, float* __restrict__ yout, float* __restrict__ yscore,
    int t0, int TC, int first, int last)
{
    __shared__ short hlds[16*264];
    __shared__ float yred[16][8];
    int tid = threadIdx.x;
    int lane = tid & 63, w = tid >> 6;
    int l15 = lane & 15, g8 = lane >> 4;
    int b0 = blockIdx.x * 16;

    // preload gamma weights (W_h padded [256][96]) as B-frags + biases
    bf16x8 gb[2][3];
    float bh[2], bhh[3][2];
    #pragma unroll
    for (int nt = 0; nt < 2; ++nt) {
        int n = w*32 + nt*16 + l15;
        #pragma unroll
        for (int kt = 0; kt < 3; ++kt)
            gb[nt][kt] = *(const bf16x8*)(whp + (size_t)n*96 + kt*32 + g8*8);
        bh[nt] = b_h[n];
        #pragma unroll
        for (int g = 0; g < 3; ++g) bhh[g][nt] = b_hh[g*H_ + n];
    }

    // carried h in C layout: h[col-tile][row-reg]; rows = g8*4+rr
    float h[2][4];
    #pragma unroll
    for (int nt = 0; nt < 2; ++nt)
        #pragma unroll
        for (int rr = 0; rr < 4; ++rr) {
            int row = g8*4 + rr, c = w*32 + nt*16 + l15;
            h[nt][rr] = first ? 0.f : hstate[(size_t)(b0+row)*H_ + c];
        }

    f32x4 z4 = {0.f,0.f,0.f,0.f};
    for (int lt = 0; lt < TC; ++lt) {
        int t = t0 + lt;
        // ---- gamma_h(t) via MFMA: A = deltas rows, B = W_h^T
        bf16x8 da[3];
        {
            const float* dbase = deltas + ((size_t)(b0 + l15)*T_ + t)*V_;
            #pragma unroll
            for (int kt = 0; kt < 3; ++kt) {
                bf16x8 tmp;
                #pragma unroll
                for (int j = 0; j < 8; ++j) {
                    int k = kt*32 + g8*8 + j;
                    float v = (k < V_) ? dbase[k] : 0.f;
                    tmp[j] = f2bs(v);
                }
                da[kt] = tmp;
            }
        }
        f32x4 gacc[2]; gacc[0] = z4; gacc[1] = z4;
        #pragma unroll
        for (int kt = 0; kt < 3; ++kt) {
            gacc[0] = __builtin_amdgcn_mfma_f32_16x16x32_bf16(da[kt], gb[0][kt], gacc[0], 0,0,0);
            gacc[1] = __builtin_amdgcn_mfma_f32_16x16x32_bf16(da[kt], gb[1][kt], gacc[1], 0,0,0);
        }
        // ---- h_dec = h * gamma (C layout, wave-local)
        float hd[2][4];
        #pragma unroll
        for (int nt = 0; nt < 2; ++nt)
            #pragma unroll
            for (int rr = 0; rr < 4; ++rr) {
                float gmm = __expf(-fmaxf(gacc[nt][rr] + bh[nt], 0.f));
                hd[nt][rr] = h[nt][rr] * gmm;
            }
        __syncthreads();   // prior step's A-frag reads complete
        #pragma unroll
        for (int nt = 0; nt < 2; ++nt)
            #pragma unroll
            for (int rr = 0; rr < 4; ++rr) {
                int row = g8*4 + rr, c = w*32 + nt*16 + l15;
                hlds[row*264 + c] = f2bs(hd[nt][rr]);
            }
        __syncthreads();   // h_dec tile published
        // ---- S = h_dec @ W_hh^T for this wave's 6 N-tiles
        f32x4 sacc[3][2];
        #pragma unroll
        for (int g = 0; g < 3; ++g) { sacc[g][0] = z4; sacc[g][1] = z4; }
        #pragma unroll
        for (int kt = 0; kt < 8; ++kt) {
            bf16x8 a = *(const bf16x8*)&hlds[l15*264 + kt*32 + g8*8];
            #pragma unroll
            for (int g = 0; g < 3; ++g)
                #pragma unroll
                for (int nt = 0; nt < 2; ++nt) {
                    int n = g*H_ + w*32 + nt*16 + l15;
                    bf16x8 bb = *(const bf16x8*)(whhb + (size_t)n*H_ + kt*32 + g8*8);
                    sacc[g][nt] = __builtin_amdgcn_mfma_f32_16x16x32_bf16(a, bb, sacc[g][nt], 0,0,0);
                }
        }
        // ---- gates
        #pragma unroll
        for (int nt = 0; nt < 2; ++nt)
            #pragma unroll
            for (int rr = 0; rr < 4; ++rr) {
                int row = g8*4 + rr;
                size_t ro = ((size_t)(b0+row)*TC + lt)*H3_;
                int c = w*32 + nt*16 + l15;
                float ir  = s2f(gi[ro + c]);
                float iz  = s2f(gi[ro + H_ + c]);
                float in_ = s2f(gi[ro + 2*H_ + c]);
                float ghr = sacc[0][nt][rr] + bhh[0][nt];
                float ghz = sacc[1][nt][rr] + bhh[1][nt];
                float ghn = sacc[2][nt][rr] + bhh[2][nt];
                float rg = sig_(ir + ghr);
                float zg = sig_(iz + ghz);
                float ng = tanh_(in_ + rg*ghn);
                h[nt][rr] = (1.f-zg)*ng + zg*hd[nt][rr];
            }
    }
    // ---- persist h
    #pragma unroll
    for (int nt = 0; nt < 2; ++nt)
        #pragma unroll
        for (int rr = 0; rr < 4; ++rr) {
            int row = g8*4 + rr, c = w*32 + nt*16 + l15;
            hstate[(size_t)(b0+row)*H_ + c] = h[nt][rr];
        }
    if (last) {
        float wc0 = W_cls[w*32 + l15], wc1 = W_cls[w*32 + 16 + l15];
        float p[4];
        #pragma unroll
        for (int rr = 0; rr < 4; ++rr) {
            p[rr] = h[0][rr]*wc0 + h[1][rr]*wc1;
            #pragma unroll
            for (int off = 8; off; off >>= 1) p[rr] += __shfl_xor(p[rr], off);
        }
        if (l15 == 0)
            #pragma unroll
            for (int rr = 0; rr < 4; ++rr) yred[g8*4 + rr][w] = p[rr];
        __syncthreads();
        if (tid < 16) {
            float s = b_cls[0];
            #pragma unroll
            for (int ww = 0; ww < 8; ++ww) s += yred[tid][ww];
            yout[b0+tid]   = s;
            yscore[b0+tid] = 1.f/(1.f+__expf(-s));
        }
    }
}

static inline size_t al256(size_t x){ return (x + 255) & ~(size_t)255; }

extern "C" void kernel_launch(void* const* d_in, const int* in_sizes, int n_in,
                              void* d_out, int out_size, void* d_ws, size_t ws_size,
                              hipStream_t stream)
{
    const float* x      = (const float*)d_in[0];
    const float* mask   = (const float*)d_in[1];
    const float* deltas = (const float*)d_in[2];
    const float* meanset= (const float*)d_in[3];
    const float* W_h    = (const float*)d_in[4];
    const float* b_h    = (const float*)d_in[5];
    const float* W_x    = (const float*)d_in[6];
    const float* b_x    = (const float*)d_in[7];
    const float* W_ih   = (const float*)d_in[8];
    const float* b_ih   = (const float*)d_in[9];
    const float* W_hh   = (const float*)d_in[10];
    const float* b_hh   = (const float*)d_in[11];
    const float* W_cls  = (const float*)d_in[12];
    const float* b_cls  = (const float*)d_in[13];

    float* out    = (float*)d_out;
    float* ximp   = out;                        // B*T*V
    float* xloss  = out + (size_t)B_*T_*V_;     // 1
    float* yout   = xloss + 1;                  // B
    float* yscore = yout + B_;                  // B

    // fixed workspace blocks
    size_t off = 0;
    size_t off_whhb = off; off = al256(off + (size_t)H3_*H_*2);     // 768x256 bf16
    size_t off_whib = off; off = al256(off + (size_t)H3_*192*2);    // 768x192 bf16 (padded)
    size_t off_whp  = off; off = al256(off + (size_t)H_*96*2);      // 256x96 bf16 (padded)
    size_t off_h    = off; off = al256(off + (size_t)B_*H_*4);
    size_t off_np   = off; off = al256(off + (size_t)T_*NW1*4);
    size_t off_dp   = off; off = al256(off + (size_t)T_*NW1*4);
    size_t off_tp   = off; off = al256(off + (size_t)T_*4);
    size_t off_gi   = off;

    int tcShift = -1;
    for (int s = 7; s >= 0; --s) {
        size_t gib = (size_t)B_*((size_t)1<<s)*H3_*2;
        if (off_gi + gib <= ws_size) { tcShift = s; break; }
    }
    if (tcShift < 0) return;
    int TC = 1 << tcShift;
    int NC = T_ / TC;

    char* ws = (char*)d_ws;
    short* whhb   = (short*)(ws + off_whhb);
    short* whib   = (short*)(ws + off_whib);
    short* whp    = (short*)(ws + off_whp);
    float* hstate = (float*)(ws + off_h);
    float* numpart= (float*)(ws + off_np);
    float* denpart= (float*)(ws + off_dp);
    float* tpart  = (float*)(ws + off_tp);
    short* gi     = (short*)(ws + off_gi);

    hipLaunchKernelGGL(k_pad_cvt, dim3((H3_*H_ +255)/256), dim3(256), 0, stream, W_hh, whhb, H3_, H_, H_);
    hipLaunchKernelGGL(k_pad_cvt, dim3((H3_*192+255)/256), dim3(256), 0, stream, W_ih, whib, H3_, V2_, 192);
    hipLaunchKernelGGL(k_pad_cvt, dim3((H_*96  +255)/256), dim3(256), 0, stream, W_h,  whp,  H_,  V_,  96);
    hipLaunchKernelGGL(k_impute, dim3(NBLK1), dim3(256), 0, stream,
                       x, mask, deltas, meanset, W_x, b_x, ximp, numpart, denpart);
    hipLaunchKernelGGL(k_loss_t, dim3(T_), dim3(256), 0, stream, numpart, denpart, tpart);
    hipLaunchKernelGGL(k_loss_final, dim3(1), dim3(128), 0, stream, tpart, xloss);

    for (int c = 0; c < NC; ++c) {
        int t0 = c * TC;
        hipLaunchKernelGGL(k_gi, dim3(B_*TC/32), dim3(256), 0, stream,
                           ximp, mask, whib, b_ih, gi, t0, tcShift);
        hipLaunchKernelGGL(k_recur, dim3(B_/16), dim3(512), 0, stream,
                           gi, whhb, whp, deltas, b_h, b_hh, W_cls, b_cls,
                           hstate, yout, yscore, t0, TC, c==0, c==NC-1);
    }
}

// Round 4
// 939.795 us; speedup vs baseline: 5.8208x; 2.0578x over previous
//
#include <hip/hip_runtime.h>

#define B_  1024
#define T_  128
#define V_  89
#define H_  256
#define H3_ 768
#define V2_ 178
#define NBLK1 356            // B_*V_ / 256
#define NW1   (NBLK1*4)      // wave partials

typedef __attribute__((ext_vector_type(8))) short bf16x8;
typedef __attribute__((ext_vector_type(4))) float f32x4;
typedef __attribute__((ext_vector_type(4))) unsigned short u16x4;

__device__ __forceinline__ short f2bs(float f){
    unsigned u = __float_as_uint(f);
    unsigned r = (u + 0x7FFFu + ((u>>16)&1u)) >> 16;
    return (short)r;
}
__device__ __forceinline__ float s2f(unsigned short s){
    return __uint_as_float(((unsigned)s) << 16);
}
__device__ __forceinline__ unsigned char f2fp8(float f){
    return (unsigned char)(__builtin_amdgcn_cvt_pk_fp8_f32(f, 0.f, 0, false) & 0xFF);
}
__device__ __forceinline__ float sig_(float x){ return 1.f/(1.f+__expf(-x)); }
__device__ __forceinline__ float tanh_(float x){ return 2.f/(1.f+__expf(-2.f*x)) - 1.f; }

// ---------------------------------------------------------------- pad+convert fp32 -> bf16
__global__ __launch_bounds__(256) void k_pad_cvt(
    const float* __restrict__ src, short* __restrict__ dst, int R, int C, int Cp)
{
    int i = blockIdx.x*256 + threadIdx.x;
    if (i >= R*Cp) return;
    int r = i / Cp, k = i - r*Cp;
    dst[i] = (k < C) ? f2bs(src[r*C + k]) : (short)0;
}

// ---------------------------------------------------------------- fp32 -> fp8 e4m3 (W_hh)
__global__ __launch_bounds__(256) void k_cvt_fp8(
    const float* __restrict__ src, unsigned char* __restrict__ dst, int n)
{
    int i = blockIdx.x*256 + threadIdx.x;  // one int (4 fp8) per thread
    if (i*4 >= n) return;
    float f0 = src[i*4+0], f1 = src[i*4+1], f2 = src[i*4+2], f3 = src[i*4+3];
    int w = __builtin_amdgcn_cvt_pk_fp8_f32(f0, f1, 0, false);
    w     = __builtin_amdgcn_cvt_pk_fp8_f32(f2, f3, w, true);
    ((int*)dst)[i] = w;
}

// ---------------------------------------------------------------- K1: imputation (no barriers)
__global__ __launch_bounds__(256) void k_impute(
    const float* __restrict__ x, const float* __restrict__ mask,
    const float* __restrict__ deltas, const float* __restrict__ meanset,
    const float* __restrict__ W_x, const float* __restrict__ b_x,
    float* __restrict__ ximp, float* __restrict__ num_part, float* __restrict__ den_part)
{
    int tid = threadIdx.x;
    int i = blockIdx.x*256 + tid;             // < 91136 exactly
    int b = i / V_, v = i - b*V_;
    float wxd = W_x[v*V_ + v];
    float bx  = b_x[v];
    float mv  = meanset[v];
    const float* xp = x      + (size_t)b*T_*V_ + v;
    const float* mp = mask   + (size_t)b*T_*V_ + v;
    const float* dp = deltas + (size_t)b*T_*V_ + v;
    float*       op = ximp   + (size_t)b*T_*V_ + v;
    float last = 0.f;
    int lane = tid & 63, wid = tid >> 6;
    int gw = blockIdx.x*4 + wid;
    for (int t = 0; t < T_; ++t) {
        float xt = xp[t*V_], m = mp[t*V_], d = dp[t*V_];
        float g = __expf(-fmaxf(fmaf(d, wxd, bx), 0.f));
        last = (m > 0.f) ? xt : last;
        float xu = g*last + (1.f-g)*mv;
        op[t*V_] = m*xt + (1.f-m)*xu;
        float nv = fabsf(xt - xu)*m;
        float dv = m;
        for (int off = 32; off; off >>= 1) {
            nv += __shfl_down(nv, off);
            dv += __shfl_down(dv, off);
        }
        if (lane == 0) { num_part[t*NW1 + gw] = nv; den_part[t*NW1 + gw] = dv; }
    }
}

// ---------------------------------------------------------------- loss stage 1
__global__ __launch_bounds__(256) void k_loss_t(
    const float* __restrict__ num_part, const float* __restrict__ den_part,
    float* __restrict__ tpart)
{
    int t = blockIdx.x, tid = threadIdx.x;
    float num = 0.f, den = 0.f;
    for (int j = tid; j < NW1; j += 256) { num += num_part[t*NW1+j]; den += den_part[t*NW1+j]; }
    for (int off = 32; off; off >>= 1) { num += __shfl_down(num, off); den += __shfl_down(den, off); }
    __shared__ float sn[4], sd[4];
    int lane = tid & 63, wid = tid >> 6;
    if (lane == 0) { sn[wid] = num; sd[wid] = den; }
    __syncthreads();
    if (tid == 0) {
        float n = sn[0]+sn[1]+sn[2]+sn[3], d = sd[0]+sd[1]+sd[2]+sd[3];
        tpart[t] = n / (d + 1e-5f);
    }
}

// ---------------------------------------------------------------- loss stage 2
__global__ __launch_bounds__(128) void k_loss_final(
    const float* __restrict__ tpart, float* __restrict__ out_loss)
{
    int tid = threadIdx.x;
    float s = tpart[tid];
    for (int off = 32; off; off >>= 1) s += __shfl_down(s, off);
    __shared__ float sp[2];
    if ((tid&63)==0) sp[tid>>6] = s;
    __syncthreads();
    if (tid==0) out_loss[0] = sp[0] + sp[1];
}

// ---------------------------------------------------------------- K4: gi GEMM via MFMA
// Row order R' = lt*B + b (t-major). Block = 32 consecutive R' (same lt, 32 batch rows).
// Output layout (fragment-native, u16x4 units):
//   idx4 = ((((IDXt*8 + wc)*3 + g)*2 + ntc)*4 + g8)*16 + l15,  IDXt = lt*64 + bt
__global__ __launch_bounds__(256) void k_gi(
    const float* __restrict__ ximp, const float* __restrict__ mask,
    const short* __restrict__ whib, const float* __restrict__ b_ih,
    unsigned short* __restrict__ gi, int t0)
{
    __shared__ short xl[32*200];
    int tid = threadIdx.x;
    int r0 = blockIdx.x * 32;
    int lt = r0 >> 10;           // /1024
    int b0 = r0 & 1023;
    int t  = t0 + lt;
    for (int i = tid; i < 32*192; i += 256) {
        int r = i / 192, k = i - (i/192)*192;
        size_t base = ((size_t)(b0 + r)*T_ + t)*V_;
        float val = 0.f;
        if (k < V_)        val = ximp[base + k];
        else if (k < V2_)  val = mask[base + (k - V_)];
        xl[r*200 + k] = f2bs(val);
    }
    __syncthreads();
    int lane = tid & 63, w = tid >> 6;
    int l15 = lane & 15, g8 = lane >> 4;
    f32x4 acc[2][12];
    f32x4 z4 = {0.f,0.f,0.f,0.f};
    #pragma unroll
    for (int mt = 0; mt < 2; ++mt)
        #pragma unroll
        for (int nt = 0; nt < 12; ++nt) acc[mt][nt] = z4;
    #pragma unroll
    for (int kt = 0; kt < 6; ++kt) {
        bf16x8 a0 = *(const bf16x8*)&xl[(l15     )*200 + kt*32 + g8*8];
        bf16x8 a1 = *(const bf16x8*)&xl[(16 + l15)*200 + kt*32 + g8*8];
        #pragma unroll
        for (int nt = 0; nt < 12; ++nt) {
            int n = w*192 + nt*16 + l15;
            bf16x8 bb = *(const bf16x8*)(whib + (size_t)n*192 + kt*32 + g8*8);
            acc[0][nt] = __builtin_amdgcn_mfma_f32_16x16x32_bf16(a0, bb, acc[0][nt], 0,0,0);
            acc[1][nt] = __builtin_amdgcn_mfma_f32_16x16x32_bf16(a1, bb, acc[1][nt], 0,0,0);
        }
    }
    #pragma unroll
    for (int mt = 0; mt < 2; ++mt) {
        int bt = (b0 + mt*16) >> 4;
        size_t IDXt = (size_t)lt*64 + bt;
        #pragma unroll
        for (int nt = 0; nt < 12; ++nt) {
            int cbase = w*192 + nt*16;
            int g   = cbase >> 8;
            int hc  = cbase & 255;
            int wc  = hc >> 5;
            int ntc = (hc >> 4) & 1;
            float bi = b_ih[cbase + l15];
            u16x4 v;
            #pragma unroll
            for (int rr = 0; rr < 4; ++rr)
                v[rr] = (unsigned short)f2bs(acc[mt][nt][rr] + bi);
            size_t idx4 = ((((IDXt*8 + wc)*3 + g)*2 + ntc)*4 + g8)*16 + l15;
            ((u16x4*)gi)[idx4] = v;
        }
    }
}

// ---------------------------------------------------------------- K5: GRU recurrence
// 64 blocks x 512 thr (8 waves). MB=16 rows. W_hh fp8 register-resident (96 VGPR).
// One barrier per step; double-buffered hlds (fp8 h_dec) and dl (bf16 deltas tile).
__global__ __launch_bounds__(512, 2) void k_recur(
    const unsigned short* __restrict__ gi, const unsigned char* __restrict__ whh8,
    const short* __restrict__ whp, const float* __restrict__ deltas,
    const float* __restrict__ b_h, const float* __restrict__ b_hh,
    const float* __restrict__ W_cls, const float* __restrict__ b_cls,
    float* __restrict__ hstate, float* __restrict__ yout, float* __restrict__ yscore,
    int t0, int TC, int first, int last)
{
    __shared__ unsigned char hlds[2][16*264];
    __shared__ short dl[2][16*96];
    __shared__ float yred[16][8];
    int tid = threadIdx.x;
    int lane = tid & 63, w = tid >> 6;
    int l15 = lane & 15, g8 = lane >> 4;
    int b0 = blockIdx.x * 16;

    // ---- preload fp8 W_hh fragments: 3 gates x 2 nt x 8 kt = 48 x i64 = 96 VGPR
    long wf[3][2][8];
    #pragma unroll
    for (int g = 0; g < 3; ++g)
        #pragma unroll
        for (int nt = 0; nt < 2; ++nt) {
            int n = g*H_ + w*32 + nt*16 + l15;
            #pragma unroll
            for (int kt = 0; kt < 8; ++kt)
                wf[g][nt][kt] = *(const long*)(whh8 + (size_t)n*H_ + kt*32 + g8*8);
        }
    // ---- gamma weights (bf16) + biases
    bf16x8 gb[2][3];
    float bh[2], bhh[3][2];
    #pragma unroll
    for (int nt = 0; nt < 2; ++nt) {
        int n = w*32 + nt*16 + l15;
        #pragma unroll
        for (int kt = 0; kt < 3; ++kt)
            gb[nt][kt] = *(const bf16x8*)(whp + (size_t)n*96 + kt*32 + g8*8);
        bh[nt] = b_h[n];
        #pragma unroll
        for (int g = 0; g < 3; ++g) bhh[g][nt] = b_hh[g*H_ + n];
    }
    // ---- carried h (C layout: row = g8*4+rr, col = w*32+nt*16+l15)
    float h[2][4];
    #pragma unroll
    for (int nt = 0; nt < 2; ++nt)
        #pragma unroll
        for (int rr = 0; rr < 4; ++rr) {
            int row = g8*4 + rr, c = w*32 + nt*16 + l15;
            h[nt][rr] = first ? 0.f : hstate[(size_t)(b0+row)*H_ + c];
        }

    // ---- prologue: stage deltas tile for t0 into dl[0]
    for (int i = tid; i < 16*96; i += 512) {
        int r = i / 96, k = i - (i/96)*96;
        float val = (k < V_) ? deltas[((size_t)(b0+r)*T_ + t0)*V_ + k] : 0.f;
        dl[0][i] = f2bs(val);
    }
    __syncthreads();

    f32x4 z4 = {0.f,0.f,0.f,0.f};
    for (int lt = 0; lt < TC; ++lt) {
        int t = t0 + lt;
        int cb = lt & 1;
        // ---- issue gi loads early (consumed at end of step)
        u16x4 gv[3][2];
        {
            size_t IDXt = (size_t)lt*64 + blockIdx.x;
            #pragma unroll
            for (int g = 0; g < 3; ++g)
                #pragma unroll
                for (int nt = 0; nt < 2; ++nt) {
                    size_t idx4 = ((((IDXt*8 + w)*3 + g)*2 + nt)*4 + g8)*16 + l15;
                    gv[g][nt] = ((const u16x4*)gi)[idx4];
                }
        }
        // ---- gamma_h via bf16 MFMA from dl[cb]
        f32x4 gacc[2]; gacc[0] = z4; gacc[1] = z4;
        #pragma unroll
        for (int kt = 0; kt < 3; ++kt) {
            bf16x8 da = *(const bf16x8*)&dl[cb][l15*96 + kt*32 + g8*8];
            gacc[0] = __builtin_amdgcn_mfma_f32_16x16x32_bf16(da, gb[0][kt], gacc[0], 0,0,0);
            gacc[1] = __builtin_amdgcn_mfma_f32_16x16x32_bf16(da, gb[1][kt], gacc[1], 0,0,0);
        }
        // ---- h_dec = h * gamma; publish fp8 tile
        float hd[2][4];
        #pragma unroll
        for (int nt = 0; nt < 2; ++nt)
            #pragma unroll
            for (int rr = 0; rr < 4; ++rr) {
                float gmm = __expf(-fmaxf(gacc[nt][rr] + bh[nt], 0.f));
                hd[nt][rr] = h[nt][rr] * gmm;
                int row = g8*4 + rr, c = w*32 + nt*16 + l15;
                hlds[cb][row*264 + c] = f2fp8(hd[nt][rr]);
            }
        // ---- stage deltas for t+1 into dl[cb^1]
        if (lt + 1 < TC) {
            for (int i = tid; i < 16*96; i += 512) {
                int r = i / 96, k = i - (i/96)*96;
                float val = (k < V_) ? deltas[((size_t)(b0+r)*T_ + (t+1))*V_ + k] : 0.f;
                dl[cb^1][i] = f2bs(val);
            }
        }
        __syncthreads();   // hlds[cb] + dl[cb^1] published; prior-step reads done
        // ---- S = h_dec @ W_hh^T  (fp8 MFMA, weights in registers)
        f32x4 sacc[3][2];
        #pragma unroll
        for (int g = 0; g < 3; ++g) { sacc[g][0] = z4; sacc[g][1] = z4; }
        #pragma unroll
        for (int kt = 0; kt < 8; ++kt) {
            long a = *(const long*)&hlds[cb][l15*264 + kt*32 + g8*8];
            #pragma unroll
            for (int g = 0; g < 3; ++g)
                #pragma unroll
                for (int nt = 0; nt < 2; ++nt)
                    sacc[g][nt] = __builtin_amdgcn_mfma_f32_16x16x32_fp8_fp8(
                        a, wf[g][nt][kt], sacc[g][nt], 0,0,0);
        }
        // ---- gates
        #pragma unroll
        for (int nt = 0; nt < 2; ++nt)
            #pragma unroll
            for (int rr = 0; rr < 4; ++rr) {
                float ir  = s2f(gv[0][nt][rr]);
                float iz  = s2f(gv[1][nt][rr]);
                float in_ = s2f(gv[2][nt][rr]);
                float rg = sig_(ir + sacc[0][nt][rr] + bhh[0][nt]);
                float zg = sig_(iz + sacc[1][nt][rr] + bhh[1][nt]);
                float ng = tanh_(in_ + rg*(sacc[2][nt][rr] + bhh[2][nt]));
                h[nt][rr] = (1.f-zg)*ng + zg*hd[nt][rr];
            }
    }
    // ---- persist h
    #pragma unroll
    for (int nt = 0; nt < 2; ++nt)
        #pragma unroll
        for (int rr = 0; rr < 4; ++rr) {
            int row = g8*4 + rr, c = w*32 + nt*16 + l15;
            hstate[(size_t)(b0+row)*H_ + c] = h[nt][rr];
        }
    if (last) {
        float wc0 = W_cls[w*32 + l15], wc1 = W_cls[w*32 + 16 + l15];
        float p[4];
        #pragma unroll
        for (int rr = 0; rr < 4; ++rr) {
            p[rr] = h[0][rr]*wc0 + h[1][rr]*wc1;
            #pragma unroll
            for (int off = 8; off; off >>= 1) p[rr] += __shfl_xor(p[rr], off);
        }
        if (l15 == 0)
            #pragma unroll
            for (int rr = 0; rr < 4; ++rr) yred[g8*4 + rr][w] = p[rr];
        __syncthreads();
        if (tid < 16) {
            float s = b_cls[0];
            #pragma unroll
            for (int ww = 0; ww < 8; ++ww) s += yred[tid][ww];
            yout[b0+tid]   = s;
            yscore[b0+tid] = 1.f/(1.f+__expf(-s));
        }
    }
}

static inline size_t al256(size_t x){ return (x + 255) & ~(size_t)255; }

extern "C" void kernel_launch(void* const* d_in, const int* in_sizes, int n_in,
                              void* d_out, int out_size, void* d_ws, size_t ws_size,
                              hipStream_t stream)
{
    const float* x      = (const float*)d_in[0];
    const float* mask   = (const float*)d_in[1];
    const float* deltas = (const float*)d_in[2];
    const float* meanset= (const float*)d_in[3];
    const float* W_h    = (const float*)d_in[4];
    const float* b_h    = (const float*)d_in[5];
    const float* W_x    = (const float*)d_in[6];
    const float* b_x    = (const float*)d_in[7];
    const float* W_ih   = (const float*)d_in[8];
    const float* b_ih   = (const float*)d_in[9];
    const float* W_hh   = (const float*)d_in[10];
    const float* b_hh   = (const float*)d_in[11];
    const float* W_cls  = (const float*)d_in[12];
    const float* b_cls  = (const float*)d_in[13];

    float* out    = (float*)d_out;
    float* ximp   = out;                        // B*T*V
    float* xloss  = out + (size_t)B_*T_*V_;     // 1
    float* yout   = xloss + 1;                  // B
    float* yscore = yout + B_;                  // B

    // fixed workspace blocks
    size_t off = 0;
    size_t off_whh8 = off; off = al256(off + (size_t)H3_*H_);       // fp8
    size_t off_whib = off; off = al256(off + (size_t)H3_*192*2);    // bf16 padded
    size_t off_whp  = off; off = al256(off + (size_t)H_*96*2);      // bf16 padded
    size_t off_h    = off; off = al256(off + (size_t)B_*H_*4);
    size_t off_np   = off; off = al256(off + (size_t)T_*NW1*4);
    size_t off_dp   = off; off = al256(off + (size_t)T_*NW1*4);
    size_t off_tp   = off; off = al256(off + (size_t)T_*4);
    size_t off_gi   = off;

    int tcShift = -1;
    for (int s = 7; s >= 0; --s) {
        size_t gib = (size_t)B_*((size_t)1<<s)*H3_*2;
        if (off_gi + gib <= ws_size) { tcShift = s; break; }
    }
    if (tcShift < 0) return;
    int TC = 1 << tcShift;
    int NC = T_ / TC;

    char* ws = (char*)d_ws;
    unsigned char* whh8 = (unsigned char*)(ws + off_whh8);
    short* whib   = (short*)(ws + off_whib);
    short* whp    = (short*)(ws + off_whp);
    float* hstate = (float*)(ws + off_h);
    float* numpart= (float*)(ws + off_np);
    float* denpart= (float*)(ws + off_dp);
    float* tpart  = (float*)(ws + off_tp);
    unsigned short* gi = (unsigned short*)(ws + off_gi);

    hipLaunchKernelGGL(k_cvt_fp8, dim3((H3_*H_/4+255)/256), dim3(256), 0, stream, W_hh, whh8, H3_*H_);
    hipLaunchKernelGGL(k_pad_cvt, dim3((H3_*192+255)/256), dim3(256), 0, stream, W_ih, whib, H3_, V2_, 192);
    hipLaunchKernelGGL(k_pad_cvt, dim3((H_*96  +255)/256), dim3(256), 0, stream, W_h,  whp,  H_,  V_,  96);
    hipLaunchKernelGGL(k_impute, dim3(NBLK1), dim3(256), 0, stream,
                       x, mask, deltas, meanset, W_x, b_x, ximp, numpart, denpart);
    hipLaunchKernelGGL(k_loss_t, dim3(T_), dim3(256), 0, stream, numpart, denpart, tpart);
    hipLaunchKernelGGL(k_loss_final, dim3(1), dim3(128), 0, stream, tpart, xloss);

    for (int c = 0; c < NC; ++c) {
        int t0 = c * TC;
        hipLaunchKernelGGL(k_gi, dim3(B_*TC/32), dim3(256), 0, stream,
                           ximp, mask, whib, b_ih, gi, t0);
        hipLaunchKernelGGL(k_recur, dim3(B_/16), dim3(512), 0, stream,
                           gi, whh8, whp, deltas, b_h, b_hh, W_cls, b_cls,
                           hstate, yout, yscore, t0, TC, c==0, c==NC-1);
    }
}

// Round 5
// 902.154 us; speedup vs baseline: 6.0636x; 1.0417x over previous
//
#include <hip/hip_runtime.h>

#define B_  1024
#define T_  128
#define V_  89
#define H_  256
#define H3_ 768
#define V2_ 178
#define NBLK1 356            // B_*V_ / 256
#define NW1   (NBLK1*4)      // wave partials

typedef __attribute__((ext_vector_type(8))) short bf16x8;
typedef __attribute__((ext_vector_type(4))) float f32x4;
typedef __attribute__((ext_vector_type(4))) unsigned short u16x4;

__device__ __forceinline__ short f2bs(float f){
    unsigned u = __float_as_uint(f);
    unsigned r = (u + 0x7FFFu + ((u>>16)&1u)) >> 16;
    return (short)r;
}
__device__ __forceinline__ float s2f(unsigned short s){
    return __uint_as_float(((unsigned)s) << 16);
}
__device__ __forceinline__ float sig_(float x){ return 1.f/(1.f+__expf(-x)); }
__device__ __forceinline__ float tanh_(float x){ return 2.f/(1.f+__expf(-2.f*x)) - 1.f; }

// ---------------------------------------------------------------- pad+convert fp32 -> bf16
__global__ __launch_bounds__(256) void k_pad_cvt(
    const float* __restrict__ src, short* __restrict__ dst, int R, int C, int Cp)
{
    int i = blockIdx.x*256 + threadIdx.x;
    if (i >= R*Cp) return;
    int r = i / Cp, k = i - r*Cp;
    dst[i] = (k < C) ? f2bs(src[r*C + k]) : (short)0;
}

// ---------------------------------------------------------------- fp32 -> fp8 e4m3 (W_hh)
__global__ __launch_bounds__(256) void k_cvt_fp8(
    const float* __restrict__ src, unsigned char* __restrict__ dst, int n)
{
    int i = blockIdx.x*256 + threadIdx.x;  // one int (4 fp8) per thread
    if (i*4 >= n) return;
    float f0 = src[i*4+0], f1 = src[i*4+1], f2 = src[i*4+2], f3 = src[i*4+3];
    int w = __builtin_amdgcn_cvt_pk_fp8_f32(f0, f1, 0, false);
    w     = __builtin_amdgcn_cvt_pk_fp8_f32(f2, f3, w, true);
    ((int*)dst)[i] = w;
}

// ---------------------------------------------------------------- K1: imputation (no barriers)
__global__ __launch_bounds__(256) void k_impute(
    const float* __restrict__ x, const float* __restrict__ mask,
    const float* __restrict__ deltas, const float* __restrict__ meanset,
    const float* __restrict__ W_x, const float* __restrict__ b_x,
    float* __restrict__ ximp, float* __restrict__ num_part, float* __restrict__ den_part)
{
    int tid = threadIdx.x;
    int i = blockIdx.x*256 + tid;             // < 91136 exactly
    int b = i / V_, v = i - b*V_;
    float wxd = W_x[v*V_ + v];
    float bx  = b_x[v];
    float mv  = meanset[v];
    const float* xp = x      + (size_t)b*T_*V_ + v;
    const float* mp = mask   + (size_t)b*T_*V_ + v;
    const float* dp = deltas + (size_t)b*T_*V_ + v;
    float*       op = ximp   + (size_t)b*T_*V_ + v;
    float last = 0.f;
    int lane = tid & 63, wid = tid >> 6;
    int gw = blockIdx.x*4 + wid;
    for (int t = 0; t < T_; ++t) {
        float xt = xp[t*V_], m = mp[t*V_], d = dp[t*V_];
        float g = __expf(-fmaxf(fmaf(d, wxd, bx), 0.f));
        last = (m > 0.f) ? xt : last;
        float xu = g*last + (1.f-g)*mv;
        op[t*V_] = m*xt + (1.f-m)*xu;
        float nv = fabsf(xt - xu)*m;
        float dv = m;
        for (int off = 32; off; off >>= 1) {
            nv += __shfl_down(nv, off);
            dv += __shfl_down(dv, off);
        }
        if (lane == 0) { num_part[t*NW1 + gw] = nv; den_part[t*NW1 + gw] = dv; }
    }
}

// ---------------------------------------------------------------- loss stage 1
__global__ __launch_bounds__(256) void k_loss_t(
    const float* __restrict__ num_part, const float* __restrict__ den_part,
    float* __restrict__ tpart)
{
    int t = blockIdx.x, tid = threadIdx.x;
    float num = 0.f, den = 0.f;
    for (int j = tid; j < NW1; j += 256) { num += num_part[t*NW1+j]; den += den_part[t*NW1+j]; }
    for (int off = 32; off; off >>= 1) { num += __shfl_down(num, off); den += __shfl_down(den, off); }
    __shared__ float sn[4], sd[4];
    int lane = tid & 63, wid = tid >> 6;
    if (lane == 0) { sn[wid] = num; sd[wid] = den; }
    __syncthreads();
    if (tid == 0) {
        float n = sn[0]+sn[1]+sn[2]+sn[3], d = sd[0]+sd[1]+sd[2]+sd[3];
        tpart[t] = n / (d + 1e-5f);
    }
}

// ---------------------------------------------------------------- loss stage 2
__global__ __launch_bounds__(128) void k_loss_final(
    const float* __restrict__ tpart, float* __restrict__ out_loss)
{
    int tid = threadIdx.x;
    float s = tpart[tid];
    for (int off = 32; off; off >>= 1) s += __shfl_down(s, off);
    __shared__ float sp[2];
    if ((tid&63)==0) sp[tid>>6] = s;
    __syncthreads();
    if (tid==0) out_loss[0] = sp[0] + sp[1];
}

// ---------------------------------------------------------------- K4: gi GEMM via MFMA
// 4 output groups per (t, batch-quarter bq): g=0,1,2 -> gates r,z,n (bf16 preact+bias)
// g=3 -> gamma_h = exp(-relu(d@W_h^T + b_h)) (bf16 value).
// u16x4 element index: idx4 = (((lt*256 + bq)*4 + g)*256 + c), rows bq*4..+3 in v[0..3]
__global__ __launch_bounds__(256) void k_gi(
    const float* __restrict__ ximp, const float* __restrict__ mask,
    const float* __restrict__ deltas,
    const short* __restrict__ whib, const short* __restrict__ whp,
    const float* __restrict__ b_ih, const float* __restrict__ b_h,
    unsigned short* __restrict__ gi, int t0)
{
    __shared__ short xl[32*200];
    __shared__ short dl2[32*104];
    int tid = threadIdx.x;
    int r0 = blockIdx.x * 32;
    int lt = r0 >> 10;
    int b0r = r0 & 1023;
    int t  = t0 + lt;
    for (int i = tid; i < 32*192; i += 256) {
        int r = i / 192, k = i - r*192;
        size_t base = ((size_t)(b0r + r)*T_ + t)*V_;
        float val = 0.f;
        if (k < V_)        val = ximp[base + k];
        else if (k < V2_)  val = mask[base + (k - V_)];
        xl[r*200 + k] = f2bs(val);
    }
    for (int i = tid; i < 32*96; i += 256) {
        int r = i / 96, k = i - r*96;
        size_t base = ((size_t)(b0r + r)*T_ + t)*V_;
        dl2[r*104 + k] = (k < V_) ? f2bs(deltas[base + k]) : (short)0;
    }
    __syncthreads();
    int lane = tid & 63, w = tid >> 6;
    int l15 = lane & 15, g8 = lane >> 4;
    f32x4 z4 = {0.f,0.f,0.f,0.f};

    // ---- gamma group (g=3): cols cg = w*64 + nt*16 + l15
    {
        f32x4 acc[2][4];
        #pragma unroll
        for (int mt = 0; mt < 2; ++mt)
            #pragma unroll
            for (int nt = 0; nt < 4; ++nt) acc[mt][nt] = z4;
        #pragma unroll
        for (int kt = 0; kt < 3; ++kt) {
            bf16x8 a0 = *(const bf16x8*)&dl2[(l15     )*104 + kt*32 + g8*8];
            bf16x8 a1 = *(const bf16x8*)&dl2[(16 + l15)*104 + kt*32 + g8*8];
            #pragma unroll
            for (int nt = 0; nt < 4; ++nt) {
                int n = w*64 + nt*16 + l15;
                bf16x8 bb = *(const bf16x8*)(whp + (size_t)n*96 + kt*32 + g8*8);
                acc[0][nt] = __builtin_amdgcn_mfma_f32_16x16x32_bf16(a0, bb, acc[0][nt], 0,0,0);
                acc[1][nt] = __builtin_amdgcn_mfma_f32_16x16x32_bf16(a1, bb, acc[1][nt], 0,0,0);
            }
        }
        #pragma unroll
        for (int mt = 0; mt < 2; ++mt) {
            int bq = (b0r + mt*16 + g8*4) >> 2;
            #pragma unroll
            for (int nt = 0; nt < 4; ++nt) {
                int c = w*64 + nt*16 + l15;
                float bb = b_h[c];
                u16x4 v;
                #pragma unroll
                for (int rr = 0; rr < 4; ++rr)
                    v[rr] = (unsigned short)f2bs(__expf(-fmaxf(acc[mt][nt][rr] + bb, 0.f)));
                size_t idx4 = (((size_t)lt*256 + bq)*4 + 3)*256 + c;
                ((u16x4*)gi)[idx4] = v;
            }
        }
    }
    // ---- r,z,n groups: cols C = w*192 + nt*16 + l15 of 768
    {
        f32x4 acc[2][12];
        #pragma unroll
        for (int mt = 0; mt < 2; ++mt)
            #pragma unroll
            for (int nt = 0; nt < 12; ++nt) acc[mt][nt] = z4;
        #pragma unroll
        for (int kt = 0; kt < 6; ++kt) {
            bf16x8 a0 = *(const bf16x8*)&xl[(l15     )*200 + kt*32 + g8*8];
            bf16x8 a1 = *(const bf16x8*)&xl[(16 + l15)*200 + kt*32 + g8*8];
            #pragma unroll
            for (int nt = 0; nt < 12; ++nt) {
                int n = w*192 + nt*16 + l15;
                bf16x8 bb = *(const bf16x8*)(whib + (size_t)n*192 + kt*32 + g8*8);
                acc[0][nt] = __builtin_amdgcn_mfma_f32_16x16x32_bf16(a0, bb, acc[0][nt], 0,0,0);
                acc[1][nt] = __builtin_amdgcn_mfma_f32_16x16x32_bf16(a1, bb, acc[1][nt], 0,0,0);
            }
        }
        #pragma unroll
        for (int mt = 0; mt < 2; ++mt) {
            int bq = (b0r + mt*16 + g8*4) >> 2;
            #pragma unroll
            for (int nt = 0; nt < 12; ++nt) {
                int C = w*192 + nt*16 + l15;
                int g = C >> 8, c = C & 255;
                float bi = b_ih[C];
                u16x4 v;
                #pragma unroll
                for (int rr = 0; rr < 4; ++rr)
                    v[rr] = (unsigned short)f2bs(acc[mt][nt][rr] + bi);
                size_t idx4 = (((size_t)lt*256 + bq)*4 + g)*256 + c;
                ((u16x4*)gi)[idx4] = v;
            }
        }
    }
}

// ---------------------------------------------------------------- K5: GRU recurrence
// 256 blocks x 1024 thr (16 waves, 4/SIMD). Block owns 4 batch rows (blk*4..+3).
// All lanes mirror the 4 valid rows (g8 duplicates). W_hh fp8 in 48 VGPR/lane.
__global__ __launch_bounds__(1024) void k_recur(
    const unsigned short* __restrict__ gi, const unsigned char* __restrict__ whh8,
    const float* __restrict__ b_hh, const float* __restrict__ W_cls,
    const float* __restrict__ b_cls,
    float* __restrict__ hstate, float* __restrict__ yout, float* __restrict__ yscore,
    int TC, int first, int last)
{
    __shared__ unsigned char hlds[2][16*272];
    __shared__ float yred[4][16];
    int tid = threadIdx.x;
    int lane = tid & 63, w16 = tid >> 6;
    int l15 = lane & 15, g8 = lane >> 4;
    int blk = blockIdx.x;
    int c = w16*16 + l15;           // owned h column

    long wf[3][8];
    #pragma unroll
    for (int g = 0; g < 3; ++g) {
        int n = g*H_ + c;
        #pragma unroll
        for (int kt = 0; kt < 8; ++kt)
            wf[g][kt] = *(const long*)(whh8 + (size_t)n*H_ + kt*32 + g8*8);
    }
    float bhh0 = b_hh[c], bhh1 = b_hh[H_ + c], bhh2 = b_hh[2*H_ + c];

    float h[4];
    #pragma unroll
    for (int rr = 0; rr < 4; ++rr)
        h[rr] = first ? 0.f : hstate[(size_t)(blk*4 + rr)*H_ + c];

    const u16x4* gp = (const u16x4*)gi;
    #define GIDX(LT,G) ((((size_t)(LT)*256 + blk)*4 + (G))*256 + c)
    u16x4 gA[4], gB[4];
    #pragma unroll
    for (int g = 0; g < 4; ++g) gA[g] = gp[GIDX(0, g)];
    #pragma unroll
    for (int g = 0; g < 4; ++g) gB[g] = gp[GIDX(1, g)];

    auto step = [&](u16x4 (&gv)[4], int cb) {
        float hd[4];
        #pragma unroll
        for (int rr = 0; rr < 4; ++rr) hd[rr] = h[rr] * s2f(gv[3][rr]);
        int p01 = __builtin_amdgcn_cvt_pk_fp8_f32(hd[0], hd[1], 0, false);
        int p23 = __builtin_amdgcn_cvt_pk_fp8_f32(hd[2], hd[3], 0, false);
        unsigned char* hp = &hlds[cb][(g8*4)*272 + c];
        hp[0]     = (unsigned char)(p01 & 0xFF);
        hp[272]   = (unsigned char)((p01 >> 8) & 0xFF);
        hp[544]   = (unsigned char)(p23 & 0xFF);
        hp[816]   = (unsigned char)((p23 >> 8) & 0xFF);
        __syncthreads();
        f32x4 s0 = {bhh0,bhh0,bhh0,bhh0};
        f32x4 s1 = {bhh1,bhh1,bhh1,bhh1};
        f32x4 s2 = {bhh2,bhh2,bhh2,bhh2};
        #pragma unroll
        for (int kt = 0; kt < 8; ++kt) {
            long a = *(const long*)&hlds[cb][l15*272 + kt*32 + g8*8];
            s0 = __builtin_amdgcn_mfma_f32_16x16x32_fp8_fp8(a, wf[0][kt], s0, 0,0,0);
            s1 = __builtin_amdgcn_mfma_f32_16x16x32_fp8_fp8(a, wf[1][kt], s1, 0,0,0);
            s2 = __builtin_amdgcn_mfma_f32_16x16x32_fp8_fp8(a, wf[2][kt], s2, 0,0,0);
        }
        #pragma unroll
        for (int rr = 0; rr < 4; ++rr) {
            float rg = sig_(s2f(gv[0][rr]) + s0[rr]);
            float zg = sig_(s2f(gv[1][rr]) + s1[rr]);
            float ng = tanh_(s2f(gv[2][rr]) + rg*s2[rr]);
            h[rr] = (1.f - zg)*ng + zg*hd[rr];
        }
    };

    for (int lt = 0; lt < TC; lt += 2) {
        step(gA, 0);
        int lA = (lt + 2 < TC) ? lt + 2 : lt;
        #pragma unroll
        for (int g = 0; g < 4; ++g) gA[g] = gp[GIDX(lA, g)];
        step(gB, 1);
        int lB = (lt + 3 < TC) ? lt + 3 : lt + 1;
        #pragma unroll
        for (int g = 0; g < 4; ++g) gB[g] = gp[GIDX(lB, g)];
    }
    #undef GIDX

    if (g8 == 0)
        #pragma unroll
        for (int rr = 0; rr < 4; ++rr)
            hstate[(size_t)(blk*4 + rr)*H_ + c] = h[rr];

    if (last) {
        float wc = W_cls[c];
        float p[4];
        #pragma unroll
        for (int rr = 0; rr < 4; ++rr) {
            p[rr] = h[rr]*wc;
            #pragma unroll
            for (int off = 8; off; off >>= 1) p[rr] += __shfl_xor(p[rr], off);
        }
        if (lane == 0)
            #pragma unroll
            for (int rr = 0; rr < 4; ++rr) yred[rr][w16] = p[rr];
        __syncthreads();
        if (tid < 4) {
            float s = b_cls[0];
            #pragma unroll
            for (int ww = 0; ww < 16; ++ww) s += yred[tid][ww];
            yout[blk*4 + tid]   = s;
            yscore[blk*4 + tid] = 1.f/(1.f+__expf(-s));
        }
    }
}

static inline size_t al256(size_t x){ return (x + 255) & ~(size_t)255; }

extern "C" void kernel_launch(void* const* d_in, const int* in_sizes, int n_in,
                              void* d_out, int out_size, void* d_ws, size_t ws_size,
                              hipStream_t stream)
{
    const float* x      = (const float*)d_in[0];
    const float* mask   = (const float*)d_in[1];
    const float* deltas = (const float*)d_in[2];
    const float* meanset= (const float*)d_in[3];
    const float* W_h    = (const float*)d_in[4];
    const float* b_h    = (const float*)d_in[5];
    const float* W_x    = (const float*)d_in[6];
    const float* b_x    = (const float*)d_in[7];
    const float* W_ih   = (const float*)d_in[8];
    const float* b_ih   = (const float*)d_in[9];
    const float* W_hh   = (const float*)d_in[10];
    const float* b_hh   = (const float*)d_in[11];
    const float* W_cls  = (const float*)d_in[12];
    const float* b_cls  = (const float*)d_in[13];

    float* out    = (float*)d_out;
    float* ximp   = out;                        // B*T*V
    float* xloss  = out + (size_t)B_*T_*V_;     // 1
    float* yout   = xloss + 1;                  // B
    float* yscore = yout + B_;                  // B

    size_t off = 0;
    size_t off_whh8 = off; off = al256(off + (size_t)H3_*H_);       // fp8
    size_t off_whib = off; off = al256(off + (size_t)H3_*192*2);    // bf16 padded
    size_t off_whp  = off; off = al256(off + (size_t)H_*96*2);      // bf16 padded
    size_t off_h    = off; off = al256(off + (size_t)B_*H_*4);
    size_t off_np   = off; off = al256(off + (size_t)T_*NW1*4);
    size_t off_dp   = off; off = al256(off + (size_t)T_*NW1*4);
    size_t off_tp   = off; off = al256(off + (size_t)T_*4);
    size_t off_gi   = off;

    int tcShift = -1;
    for (int s = 7; s >= 1; --s) {
        size_t gib = (size_t)B_*((size_t)1<<s)*1024*2;   // 4 groups x 256 cols, bf16
        if (off_gi + gib <= ws_size) { tcShift = s; break; }
    }
    if (tcShift < 0) return;
    int TC = 1 << tcShift;
    int NC = T_ / TC;

    char* ws = (char*)d_ws;
    unsigned char* whh8 = (unsigned char*)(ws + off_whh8);
    short* whib   = (short*)(ws + off_whib);
    short* whp    = (short*)(ws + off_whp);
    float* hstate = (float*)(ws + off_h);
    float* numpart= (float*)(ws + off_np);
    float* denpart= (float*)(ws + off_dp);
    float* tpart  = (float*)(ws + off_tp);
    unsigned short* gi = (unsigned short*)(ws + off_gi);

    hipLaunchKernelGGL(k_cvt_fp8, dim3((H3_*H_/4+255)/256), dim3(256), 0, stream, W_hh, whh8, H3_*H_);
    hipLaunchKernelGGL(k_pad_cvt, dim3((H3_*192+255)/256), dim3(256), 0, stream, W_ih, whib, H3_, V2_, 192);
    hipLaunchKernelGGL(k_pad_cvt, dim3((H_*96  +255)/256), dim3(256), 0, stream, W_h,  whp,  H_,  V_,  96);
    hipLaunchKernelGGL(k_impute, dim3(NBLK1), dim3(256), 0, stream,
                       x, mask, deltas, meanset, W_x, b_x, ximp, numpart, denpart);
    hipLaunchKernelGGL(k_loss_t, dim3(T_), dim3(256), 0, stream, numpart, denpart, tpart);
    hipLaunchKernelGGL(k_loss_final, dim3(1), dim3(128), 0, stream, tpart, xloss);

    for (int ci = 0; ci < NC; ++ci) {
        int t0 = ci * TC;
        hipLaunchKernelGGL(k_gi, dim3(B_*TC/32), dim3(256), 0, stream,
                           ximp, mask, deltas, whib, whp, b_ih, b_h, gi, t0);
        hipLaunchKernelGGL(k_recur, dim3(B_/4), dim3(1024), 0, stream,
                           gi, whh8, b_hh, W_cls, b_cls,
                           hstate, yout, yscore, TC, ci==0, ci==NC-1);
    }
}

// Round 6
// 780.909 us; speedup vs baseline: 7.0051x; 1.1553x over previous
//
#include <hip/hip_runtime.h>

#define B_  1024
#define T_  128
#define V_  89
#define H_  256
#define H3_ 768
#define V2_ 178
#define PT_ 8            // timesteps per phase
#define NPH 16           // phases (PT_*NPH = T_)
#define NB2 256          // blocks in fused kernel

typedef __attribute__((ext_vector_type(8))) short bf16x8;
typedef __attribute__((ext_vector_type(4))) float f32x4;
typedef __attribute__((ext_vector_type(4))) unsigned short u16x4;

__device__ __forceinline__ short f2bs(float f){
    unsigned u = __float_as_uint(f);
    unsigned r = (u + 0x7FFFu + ((u>>16)&1u)) >> 16;
    return (short)r;
}
__device__ __forceinline__ float s2f(unsigned short s){
    return __uint_as_float(((unsigned)s) << 16);
}
__device__ __forceinline__ float sig_(float x){ return 1.f/(1.f+__expf(-x)); }
__device__ __forceinline__ float tanh_(float x){ return 2.f/(1.f+__expf(-2.f*x)) - 1.f; }

// ---------------------------------------------------------------- pad+convert fp32 -> bf16
__global__ __launch_bounds__(256) void k_pad_cvt(
    const float* __restrict__ src, short* __restrict__ dst, int R, int C, int Cp)
{
    int i = blockIdx.x*256 + threadIdx.x;
    if (i >= R*Cp) return;
    int r = i / Cp, k = i - r*Cp;
    dst[i] = (k < C) ? f2bs(src[r*C + k]) : (short)0;
}

// ---------------------------------------------------------------- fp32 -> fp8 e4m3 (W_hh)
__global__ __launch_bounds__(256) void k_cvt_fp8(
    const float* __restrict__ src, unsigned char* __restrict__ dst, int n)
{
    int i = blockIdx.x*256 + threadIdx.x;
    if (i*4 >= n) return;
    float f0 = src[i*4+0], f1 = src[i*4+1], f2 = src[i*4+2], f3 = src[i*4+3];
    int w = __builtin_amdgcn_cvt_pk_fp8_f32(f0, f1, 0, false);
    w     = __builtin_amdgcn_cvt_pk_fp8_f32(f2, f3, w, true);
    ((int*)dst)[i] = w;
}

// ---------------------------------------------------------------- fused impute+gi+gamma+recurrence
// 256 blocks x 1024 thr (16 waves). Block owns batch rows blk*4..+3 for all T.
__global__ __launch_bounds__(1024) void k_fused(
    const float* __restrict__ x, const float* __restrict__ mask,
    const float* __restrict__ deltas, const float* __restrict__ meanset,
    const float* __restrict__ W_x, const float* __restrict__ b_x,
    const short* __restrict__ whib, const short* __restrict__ whp,
    const unsigned char* __restrict__ whh8,
    const float* __restrict__ b_ih, const float* __restrict__ b_h,
    const float* __restrict__ b_hh,
    const float* __restrict__ W_cls, const float* __restrict__ b_cls,
    float* __restrict__ ximp, float* __restrict__ numpart, float* __restrict__ denpart,
    float* __restrict__ yout, float* __restrict__ yscore)
{
    // gi tile: [lt][group g][col c] -> u16x4 over 4 batch rows.  64 KB
    __shared__ u16x4 gl[PT_*4*256];
    __shared__ short xl[32*200]  __attribute__((aligned(16)));   // [x_h|m] rows lt*4+bl
    __shared__ short dl2[32*104] __attribute__((aligned(16)));   // deltas rows
    __shared__ unsigned char hlds[2][16*272] __attribute__((aligned(16)));
    __shared__ float lossn[PT_][360], lossd[PT_][360];
    __shared__ float yred[4][16];

    int tid = threadIdx.x;
    int lane = tid & 63, wv = tid >> 6;
    int l15 = lane & 15, g8 = lane >> 4;
    int blk = blockIdx.x;
    int c = wv*16 + l15;            // owned h column (0..255)

    // zero pads of xl (cols 178..191) and dl2 (cols 89..95)
    for (int i = tid; i < 32*14; i += 1024) xl[(i/14)*200 + 178 + (i%14)] = 0;
    for (int i = tid; i < 32*7;  i += 1024) dl2[(i/7)*104 + 89 + (i%7)] = 0;

    // ---- owner threads: one per (bl, v)
    bool own = (tid < 4*V_);
    int bl_o = tid / V_, v_o = tid - bl_o*V_;
    int b_o  = blk*4 + bl_o;
    float wxd = 0.f, bx = 0.f, mnv = 0.f, last = 0.f;
    float xv[PT_], mv[PT_], dv[PT_];
    if (own) {
        wxd = W_x[v_o*V_ + v_o]; bx = b_x[v_o]; mnv = meanset[v_o];
        const float* xb = x      + (size_t)b_o*T_*V_ + v_o;
        const float* mb = mask   + (size_t)b_o*T_*V_ + v_o;
        const float* db = deltas + (size_t)b_o*T_*V_ + v_o;
        #pragma unroll
        for (int lt = 0; lt < PT_; ++lt) {
            xv[lt] = xb[lt*V_]; mv[lt] = mb[lt*V_]; dv[lt] = db[lt*V_];
        }
    }

    // ---- fp8 W_hh fragments: 3 gates x 8 kt = 24 x i64 = 48 VGPR
    long wf[3][8];
    #pragma unroll
    for (int g = 0; g < 3; ++g) {
        int n = g*H_ + c;
        #pragma unroll
        for (int kt = 0; kt < 8; ++kt)
            wf[g][kt] = *(const long*)(whh8 + (size_t)n*H_ + kt*32 + g8*8);
    }
    float bhh0 = b_hh[c], bhh1 = b_hh[H_ + c], bhh2 = b_hh[2*H_ + c];

    float h[4] = {0.f, 0.f, 0.f, 0.f};
    f32x4 z4 = {0.f,0.f,0.f,0.f};

    for (int p = 0; p < NPH; ++p) {
        // ================= stage: impute + ffill + loss + LDS tiles
        if (own) {
            #pragma unroll
            for (int lt = 0; lt < PT_; ++lt) {
                int t = p*PT_ + lt;
                float xt = xv[lt], m = mv[lt], d = dv[lt];
                float gx = __expf(-fmaxf(fmaf(d, wxd, bx), 0.f));
                last = (m > 0.f) ? xt : last;
                float xu = gx*last + (1.f-gx)*mnv;
                float xh = m*xt + (1.f-m)*xu;
                ximp[((size_t)b_o*T_ + t)*V_ + v_o] = xh;
                int row = lt*4 + bl_o;
                xl[row*200 + v_o]      = f2bs(xh);
                xl[row*200 + V_ + v_o] = f2bs(m);
                dl2[row*104 + v_o]     = f2bs(d);
                lossn[lt][tid] = fabsf(xt - xu)*m;
                lossd[lt][tid] = m;
            }
        }
        __syncthreads();                         // tiles + loss partials visible

        // ---- loss reduce (wave 0 only)
        if (tid < 64) {
            int lt = tid >> 3, part = tid & 7;
            float n = 0.f, ds = 0.f;
            for (int j = part; j < 4*V_; j += 8) { n += lossn[lt][j]; ds += lossd[lt][j]; }
            n += __shfl_xor(n, 1); ds += __shfl_xor(ds, 1);
            n += __shfl_xor(n, 2); ds += __shfl_xor(ds, 2);
            n += __shfl_xor(n, 4); ds += __shfl_xor(ds, 4);
            if (part == 0) {
                int t = p*PT_ + lt;
                numpart[t*NB2 + blk] = n;
                denpart[t*NB2 + blk] = ds;
            }
        }

        // ================= GEMM phase -> gl (gates r,z,n for waves 0..11; gamma for 12..15)
        {
            f32x4 acc[2][4];
            #pragma unroll
            for (int mt = 0; mt < 2; ++mt)
                #pragma unroll
                for (int nt = 0; nt < 4; ++nt) acc[mt][nt] = z4;
            if (wv < 12) {
                #pragma unroll
                for (int kt = 0; kt < 6; ++kt) {
                    bf16x8 a0 = *(const bf16x8*)&xl[(l15     )*200 + kt*32 + g8*8];
                    bf16x8 a1 = *(const bf16x8*)&xl[(16 + l15)*200 + kt*32 + g8*8];
                    #pragma unroll
                    for (int nt = 0; nt < 4; ++nt) {
                        int C = wv*64 + nt*16 + l15;
                        bf16x8 bb = *(const bf16x8*)(whib + (size_t)C*192 + kt*32 + g8*8);
                        acc[0][nt] = __builtin_amdgcn_mfma_f32_16x16x32_bf16(a0, bb, acc[0][nt], 0,0,0);
                        acc[1][nt] = __builtin_amdgcn_mfma_f32_16x16x32_bf16(a1, bb, acc[1][nt], 0,0,0);
                    }
                }
                #pragma unroll
                for (int mt = 0; mt < 2; ++mt) {
                    int lt = mt*4 + g8;
                    #pragma unroll
                    for (int nt = 0; nt < 4; ++nt) {
                        int C = wv*64 + nt*16 + l15;
                        int g = C >> 8, cc = C & 255;
                        float bi = b_ih[C];
                        unsigned short* gp = (unsigned short*)&gl[(lt*4 + g)*256 + cc];
                        #pragma unroll
                        for (int rr = 0; rr < 4; ++rr)
                            gp[rr] = (unsigned short)f2bs(acc[mt][nt][rr] + bi);
                    }
                }
            } else {
                #pragma unroll
                for (int kt = 0; kt < 3; ++kt) {
                    bf16x8 a0 = *(const bf16x8*)&dl2[(l15     )*104 + kt*32 + g8*8];
                    bf16x8 a1 = *(const bf16x8*)&dl2[(16 + l15)*104 + kt*32 + g8*8];
                    #pragma unroll
                    for (int nt = 0; nt < 4; ++nt) {
                        int Cg = (wv-12)*64 + nt*16 + l15;
                        bf16x8 bb = *(const bf16x8*)(whp + (size_t)Cg*96 + kt*32 + g8*8);
                        acc[0][nt] = __builtin_amdgcn_mfma_f32_16x16x32_bf16(a0, bb, acc[0][nt], 0,0,0);
                        acc[1][nt] = __builtin_amdgcn_mfma_f32_16x16x32_bf16(a1, bb, acc[1][nt], 0,0,0);
                    }
                }
                #pragma unroll
                for (int mt = 0; mt < 2; ++mt) {
                    int lt = mt*4 + g8;
                    #pragma unroll
                    for (int nt = 0; nt < 4; ++nt) {
                        int Cg = (wv-12)*64 + nt*16 + l15;
                        float bi = b_h[Cg];
                        unsigned short* gp = (unsigned short*)&gl[(lt*4 + 3)*256 + Cg];
                        #pragma unroll
                        for (int rr = 0; rr < 4; ++rr)
                            gp[rr] = (unsigned short)f2bs(__expf(-fmaxf(acc[mt][nt][rr] + bi, 0.f)));
                    }
                }
            }
        }

        // ---- prefetch next phase's x/mask/deltas (hidden under recurrence)
        if (p + 1 < NPH && own) {
            const float* xb = x      + ((size_t)b_o*T_ + (p+1)*PT_)*V_ + v_o;
            const float* mb = mask   + ((size_t)b_o*T_ + (p+1)*PT_)*V_ + v_o;
            const float* db = deltas + ((size_t)b_o*T_ + (p+1)*PT_)*V_ + v_o;
            #pragma unroll
            for (int lt = 0; lt < PT_; ++lt) {
                xv[lt] = xb[lt*V_]; mv[lt] = mb[lt*V_]; dv[lt] = db[lt*V_];
            }
        }
        __syncthreads();                         // gl ready

        // ================= recurrence: 8 steps
        for (int lt = 0; lt < PT_; ++lt) {
            int cb = lt & 1;
            u16x4 gv0 = gl[(lt*4 + 0)*256 + c];
            u16x4 gv1 = gl[(lt*4 + 1)*256 + c];
            u16x4 gv2 = gl[(lt*4 + 2)*256 + c];
            u16x4 gv3 = gl[(lt*4 + 3)*256 + c];
            float hd[4];
            #pragma unroll
            for (int rr = 0; rr < 4; ++rr) hd[rr] = h[rr] * s2f(gv3[rr]);
            int p01 = __builtin_amdgcn_cvt_pk_fp8_f32(hd[0], hd[1], 0, false);
            int p23 = __builtin_amdgcn_cvt_pk_fp8_f32(hd[2], hd[3], 0, false);
            unsigned char* hp = &hlds[cb][(g8*4)*272 + c];
            hp[0]   = (unsigned char)(p01 & 0xFF);
            hp[272] = (unsigned char)((p01 >> 8) & 0xFF);
            hp[544] = (unsigned char)(p23 & 0xFF);
            hp[816] = (unsigned char)((p23 >> 8) & 0xFF);
            __syncthreads();
            f32x4 s0 = {bhh0,bhh0,bhh0,bhh0};
            f32x4 s1 = {bhh1,bhh1,bhh1,bhh1};
            f32x4 s2 = {bhh2,bhh2,bhh2,bhh2};
            #pragma unroll
            for (int kt = 0; kt < 8; ++kt) {
                long a = *(const long*)&hlds[cb][l15*272 + kt*32 + g8*8];
                s0 = __builtin_amdgcn_mfma_f32_16x16x32_fp8_fp8(a, wf[0][kt], s0, 0,0,0);
                s1 = __builtin_amdgcn_mfma_f32_16x16x32_fp8_fp8(a, wf[1][kt], s1, 0,0,0);
                s2 = __builtin_amdgcn_mfma_f32_16x16x32_fp8_fp8(a, wf[2][kt], s2, 0,0,0);
            }
            #pragma unroll
            for (int rr = 0; rr < 4; ++rr) {
                float rg = sig_(s2f(gv0[rr]) + s0[rr]);
                float zg = sig_(s2f(gv1[rr]) + s1[rr]);
                float ng = tanh_(s2f(gv2[rr]) + rg*s2[rr]);
                h[rr] = (1.f - zg)*ng + zg*hd[rr];
            }
        }
    }

    // ================= epilogue: y_out / y_score
    {
        float wc = W_cls[c];
        float pr[4];
        #pragma unroll
        for (int rr = 0; rr < 4; ++rr) {
            pr[rr] = h[rr]*wc;
            #pragma unroll
            for (int off = 8; off; off >>= 1) pr[rr] += __shfl_xor(pr[rr], off);
        }
        if (lane == 0)
            #pragma unroll
            for (int rr = 0; rr < 4; ++rr) yred[rr][wv] = pr[rr];
        __syncthreads();
        if (tid < 4) {
            float s = b_cls[0];
            #pragma unroll
            for (int ww = 0; ww < 16; ++ww) s += yred[tid][ww];
            yout[blk*4 + tid]   = s;
            yscore[blk*4 + tid] = 1.f/(1.f+__expf(-s));
        }
    }
}

// ---------------------------------------------------------------- loss stage 1: per-t
__global__ __launch_bounds__(256) void k_loss_t(
    const float* __restrict__ numpart, const float* __restrict__ denpart,
    float* __restrict__ tpart)
{
    int t = blockIdx.x, tid = threadIdx.x;
    float n = numpart[t*NB2 + tid];
    float d = denpart[t*NB2 + tid];
    for (int off = 32; off; off >>= 1) { n += __shfl_down(n, off); d += __shfl_down(d, off); }
    __shared__ float sn[4], sd[4];
    int lane = tid & 63, wid = tid >> 6;
    if (lane == 0) { sn[wid] = n; sd[wid] = d; }
    __syncthreads();
    if (tid == 0) {
        float nn = sn[0]+sn[1]+sn[2]+sn[3], dd = sd[0]+sd[1]+sd[2]+sd[3];
        tpart[t] = nn / (dd + 1e-5f);
    }
}

// ---------------------------------------------------------------- loss stage 2
__global__ __launch_bounds__(128) void k_loss_final(
    const float* __restrict__ tpart, float* __restrict__ out_loss)
{
    int tid = threadIdx.x;
    float s = tpart[tid];
    for (int off = 32; off; off >>= 1) s += __shfl_down(s, off);
    __shared__ float sp[2];
    if ((tid&63)==0) sp[tid>>6] = s;
    __syncthreads();
    if (tid==0) out_loss[0] = sp[0] + sp[1];
}

static inline size_t al256(size_t x){ return (x + 255) & ~(size_t)255; }

extern "C" void kernel_launch(void* const* d_in, const int* in_sizes, int n_in,
                              void* d_out, int out_size, void* d_ws, size_t ws_size,
                              hipStream_t stream)
{
    const float* x      = (const float*)d_in[0];
    const float* mask   = (const float*)d_in[1];
    const float* deltas = (const float*)d_in[2];
    const float* meanset= (const float*)d_in[3];
    const float* W_h    = (const float*)d_in[4];
    const float* b_h    = (const float*)d_in[5];
    const float* W_x    = (const float*)d_in[6];
    const float* b_x    = (const float*)d_in[7];
    const float* W_ih   = (const float*)d_in[8];
    const float* b_ih   = (const float*)d_in[9];
    const float* W_hh   = (const float*)d_in[10];
    const float* b_hh   = (const float*)d_in[11];
    const float* W_cls  = (const float*)d_in[12];
    const float* b_cls  = (const float*)d_in[13];

    float* out    = (float*)d_out;
    float* ximp   = out;                        // B*T*V
    float* xloss  = out + (size_t)B_*T_*V_;     // 1
    float* yout   = xloss + 1;                  // B
    float* yscore = yout + B_;                  // B

    size_t off = 0;
    size_t off_whh8 = off; off = al256(off + (size_t)H3_*H_);       // fp8
    size_t off_whib = off; off = al256(off + (size_t)H3_*192*2);    // bf16 padded
    size_t off_whp  = off; off = al256(off + (size_t)H_*96*2);      // bf16 padded
    size_t off_np   = off; off = al256(off + (size_t)T_*NB2*4);
    size_t off_dp   = off; off = al256(off + (size_t)T_*NB2*4);
    size_t off_tp   = off; off = al256(off + (size_t)T_*4);
    if (off > ws_size) return;

    char* ws = (char*)d_ws;
    unsigned char* whh8 = (unsigned char*)(ws + off_whh8);
    short* whib   = (short*)(ws + off_whib);
    short* whp    = (short*)(ws + off_whp);
    float* numpart= (float*)(ws + off_np);
    float* denpart= (float*)(ws + off_dp);
    float* tpart  = (float*)(ws + off_tp);

    hipLaunchKernelGGL(k_cvt_fp8, dim3((H3_*H_/4+255)/256), dim3(256), 0, stream, W_hh, whh8, H3_*H_);
    hipLaunchKernelGGL(k_pad_cvt, dim3((H3_*192+255)/256), dim3(256), 0, stream, W_ih, whib, H3_, V2_, 192);
    hipLaunchKernelGGL(k_pad_cvt, dim3((H_*96  +255)/256), dim3(256), 0, stream, W_h,  whp,  H_,  V_,  96);
    hipLaunchKernelGGL(k_fused, dim3(NB2), dim3(1024), 0, stream,
                       x, mask, deltas, meanset, W_x, b_x,
                       whib, whp, whh8, b_ih, b_h, b_hh, W_cls, b_cls,
                       ximp, numpart, denpart, yout, yscore);
    hipLaunchKernelGGL(k_loss_t, dim3(T_), dim3(256), 0, stream, numpart, denpart, tpart);
    hipLaunchKernelGGL(k_loss_final, dim3(1), dim3(128), 0, stream, tpart, xloss);
}

// Round 7
// 604.836 us; speedup vs baseline: 9.0443x; 1.2911x over previous
//
#include <hip/hip_runtime.h>

#define B_  1024
#define T_  128
#define V_  89
#define H_  256
#define H3_ 768
#define V2_ 178
#define PT_ 4            // timesteps per phase
#define NPH 32           // phases
#define NB2 256          // blocks in fused kernel

typedef __attribute__((ext_vector_type(8))) short bf16x8;
typedef __attribute__((ext_vector_type(4))) float f32x4;

__device__ __forceinline__ short f2bs(float f){
    unsigned u = __float_as_uint(f);
    unsigned r = (u + 0x7FFFu + ((u>>16)&1u)) >> 16;
    return (short)r;
}
__device__ __forceinline__ float sig_(float x){ return 1.f/(1.f+__expf(-x)); }
__device__ __forceinline__ float tanh_(float x){ return 2.f/(1.f+__expf(-2.f*x)) - 1.f; }

// ---------------------------------------------------------------- pad+convert fp32 -> bf16
__global__ __launch_bounds__(256) void k_pad_cvt(
    const float* __restrict__ src, short* __restrict__ dst, int R, int C, int Cp)
{
    int i = blockIdx.x*256 + threadIdx.x;
    if (i >= R*Cp) return;
    int r = i / Cp, k = i - r*Cp;
    dst[i] = (k < C) ? f2bs(src[r*C + k]) : (short)0;
}

// ---------------------------------------------------------------- fp32 -> fp8 e4m3 (W_hh)
__global__ __launch_bounds__(256) void k_cvt_fp8(
    const float* __restrict__ src, unsigned char* __restrict__ dst, int n)
{
    int i = blockIdx.x*256 + threadIdx.x;
    if (i*4 >= n) return;
    float f0 = src[i*4+0], f1 = src[i*4+1], f2 = src[i*4+2], f3 = src[i*4+3];
    int w = __builtin_amdgcn_cvt_pk_fp8_f32(f0, f1, 0, false);
    w     = __builtin_amdgcn_cvt_pk_fp8_f32(f2, f3, w, true);
    ((int*)dst)[i] = w;
}

// ---------------------------------------------------------------- fused kernel
// 256 blocks x 1024 thr (16 waves). Block owns 4 batch rows.
// Lane (wv,l15,g8) owns (row=g8, col=wv*16+l15); h is ONE scalar per lane.
// Gates GEMM M-rows: m = row*4 + lt  ->  C-frag (g8,rr) == (row g8, lt rr). Registers!
__global__ __launch_bounds__(1024) void k_fused(
    const float* __restrict__ x, const float* __restrict__ mask,
    const float* __restrict__ deltas, const float* __restrict__ meanset,
    const float* __restrict__ W_x, const float* __restrict__ b_x,
    const short* __restrict__ whib, const short* __restrict__ whp,
    const unsigned char* __restrict__ whh8,
    const float* __restrict__ b_ih, const float* __restrict__ b_h,
    const float* __restrict__ b_hh,
    const float* __restrict__ W_cls, const float* __restrict__ b_cls,
    float* __restrict__ ximp, float* __restrict__ numpart, float* __restrict__ denpart,
    float* __restrict__ yout, float* __restrict__ yscore)
{
    __shared__ short xl[16*200]  __attribute__((aligned(16)));   // m=row*4+lt, [x_h|m] pad->192
    __shared__ short dl2[16*104] __attribute__((aligned(16)));   // deltas pad->96
    __shared__ unsigned char hlds[2][16*272] __attribute__((aligned(16)));
    __shared__ float lossn[PT_][360], lossd[PT_][360];
    __shared__ float yred[4][16];

    int tid = threadIdx.x;
    int lane = tid & 63, wv = tid >> 6;
    int l15 = lane & 15, g8 = lane >> 4;
    int blk = blockIdx.x;
    int c = wv*16 + l15;            // owned column 0..255

    // zero static pads once
    for (int i = tid; i < 16*22; i += 1024) xl[(i/22)*200 + 178 + (i%22)] = 0;
    for (int i = tid; i < 16*15; i += 1024) dl2[(i/15)*104 + 89 + (i%15)] = 0;

    // ---- owners: one per (row, v); 356 threads
    bool own = (tid < 4*V_);
    int r_o = tid / V_, v_o = tid - r_o*V_;
    int b_o = blk*4 + r_o;
    float wxd = 0.f, bx = 0.f, mnv = 0.f, last = 0.f;
    if (own) { wxd = W_x[v_o*V_ + v_o]; bx = b_x[v_o]; mnv = meanset[v_o]; }

    // ---- fp8 W_hh fragments (reg-resident): 3 gates x 8 kt = 48 VGPR
    long wf[3][8];
    #pragma unroll
    for (int g = 0; g < 3; ++g) {
        #pragma unroll
        for (int kt = 0; kt < 8; ++kt)
            wf[g][kt] = *(const long*)(whh8 + (size_t)(g*H_ + c)*H_ + kt*32 + g8*8);
    }
    // gamma B-frags (constant): 3 x bf16x8 = 12 VGPR
    bf16x8 gb[3];
    #pragma unroll
    for (int kt = 0; kt < 3; ++kt)
        gb[kt] = *(const bf16x8*)(whp + (size_t)c*96 + kt*32 + g8*8);

    float bhh0 = b_hh[c], bhh1 = b_hh[H_ + c], bhh2 = b_hh[2*H_ + c];
    float bir = b_ih[c], biz = b_ih[H_ + c], bin = b_ih[2*H_ + c];
    float bhg = b_h[c];

    float h = 0.f;

    for (int p = 0; p < NPH; ++p) {
        // ================= stage: impute + ffill + loss + LDS tiles
        if (own) {
            const float* xb = x      + ((size_t)b_o*T_ + p*PT_)*V_ + v_o;
            const float* mb = mask   + ((size_t)b_o*T_ + p*PT_)*V_ + v_o;
            const float* db = deltas + ((size_t)b_o*T_ + p*PT_)*V_ + v_o;
            float xv[PT_], mv[PT_], dv[PT_];
            #pragma unroll
            for (int lt = 0; lt < PT_; ++lt) {
                xv[lt] = xb[lt*V_]; mv[lt] = mb[lt*V_]; dv[lt] = db[lt*V_];
            }
            #pragma unroll
            for (int lt = 0; lt < PT_; ++lt) {
                float xt = xv[lt], m = mv[lt], d = dv[lt];
                float gx = __expf(-fmaxf(fmaf(d, wxd, bx), 0.f));
                last = (m > 0.f) ? xt : last;
                float xu = gx*last + (1.f-gx)*mnv;
                float xh = m*xt + (1.f-m)*xu;
                ximp[((size_t)b_o*T_ + p*PT_ + lt)*V_ + v_o] = xh;
                int mr = r_o*4 + lt;
                xl[mr*200 + v_o]      = f2bs(xh);
                xl[mr*200 + V_ + v_o] = f2bs(m);
                dl2[mr*104 + v_o]     = f2bs(d);
                lossn[lt][tid] = fabsf(xt - xu)*m;
                lossd[lt][tid] = m;
            }
        }
        __syncthreads();

        // ---- loss reduce (wave 0): 16 lanes per lt
        if (tid < 64) {
            int lt = tid >> 4, part = tid & 15;
            float n = 0.f, ds = 0.f;
            for (int j = part; j < 4*V_; j += 16) { n += lossn[lt][j]; ds += lossd[lt][j]; }
            n += __shfl_xor(n, 1); ds += __shfl_xor(ds, 1);
            n += __shfl_xor(n, 2); ds += __shfl_xor(ds, 2);
            n += __shfl_xor(n, 4); ds += __shfl_xor(ds, 4);
            n += __shfl_xor(n, 8); ds += __shfl_xor(ds, 8);
            if (part == 0) {
                int t = p*PT_ + lt;
                numpart[t*NB2 + blk] = n;
                denpart[t*NB2 + blk] = ds;
            }
        }

        // ================= GEMM: gates (K=192) + gamma (K=96), all in registers
        f32x4 accr = {bir,bir,bir,bir};
        f32x4 accz = {biz,biz,biz,biz};
        f32x4 accn = {bin,bin,bin,bin};
        f32x4 gac  = {bhg,bhg,bhg,bhg};
        #pragma unroll
        for (int kt = 0; kt < 6; ++kt) {
            bf16x8 a  = *(const bf16x8*)&xl[l15*200 + kt*32 + g8*8];
            bf16x8 br = *(const bf16x8*)(whib + (size_t)(       c)*192 + kt*32 + g8*8);
            bf16x8 bz = *(const bf16x8*)(whib + (size_t)(H_  + c)*192 + kt*32 + g8*8);
            bf16x8 bn = *(const bf16x8*)(whib + (size_t)(2*H_+ c)*192 + kt*32 + g8*8);
            accr = __builtin_amdgcn_mfma_f32_16x16x32_bf16(a, br, accr, 0,0,0);
            accz = __builtin_amdgcn_mfma_f32_16x16x32_bf16(a, bz, accz, 0,0,0);
            accn = __builtin_amdgcn_mfma_f32_16x16x32_bf16(a, bn, accn, 0,0,0);
        }
        #pragma unroll
        for (int kt = 0; kt < 3; ++kt) {
            bf16x8 da = *(const bf16x8*)&dl2[l15*104 + kt*32 + g8*8];
            gac = __builtin_amdgcn_mfma_f32_16x16x32_bf16(da, gb[kt], gac, 0,0,0);
        }
        f32x4 gd;
        #pragma unroll
        for (int rr = 0; rr < 4; ++rr) gd[rr] = __expf(-fmaxf(gac[rr], 0.f));

        // ================= recurrence: PT_ steps, gates/gamma from registers
        #pragma unroll
        for (int lt = 0; lt < PT_; ++lt) {
            const int cb = lt & 1;
            float hd = h * gd[lt];
            unsigned char hb = (unsigned char)(__builtin_amdgcn_cvt_pk_fp8_f32(hd, hd, 0, false) & 0xFF);
            // 4 replica rows m = g8*4+k so A-tile is M=16
            unsigned char* hp = &hlds[cb][(g8*4)*272 + c];
            hp[0] = hb; hp[272] = hb; hp[544] = hb; hp[816] = hb;
            __syncthreads();
            f32x4 s0 = {bhh0,bhh0,bhh0,bhh0};
            f32x4 s1 = {bhh1,bhh1,bhh1,bhh1};
            f32x4 s2 = {bhh2,bhh2,bhh2,bhh2};
            #pragma unroll
            for (int kt = 0; kt < 8; ++kt) {
                long a = *(const long*)&hlds[cb][l15*272 + kt*32 + g8*8];
                s0 = __builtin_amdgcn_mfma_f32_16x16x32_fp8_fp8(a, wf[0][kt], s0, 0,0,0);
                s1 = __builtin_amdgcn_mfma_f32_16x16x32_fp8_fp8(a, wf[1][kt], s1, 0,0,0);
                s2 = __builtin_amdgcn_mfma_f32_16x16x32_fp8_fp8(a, wf[2][kt], s2, 0,0,0);
            }
            float rg = sig_(accr[lt] + s0[0]);
            float zg = sig_(accz[lt] + s1[0]);
            float ng = tanh_(accn[lt] + rg*s2[0]);
            h = (1.f - zg)*ng + zg*hd;
        }
    }

    // ================= epilogue: y_out / y_score  (lane holds h[row g8][col c])
    {
        float pr = h * W_cls[c];
        pr += __shfl_xor(pr, 1);
        pr += __shfl_xor(pr, 2);
        pr += __shfl_xor(pr, 4);
        pr += __shfl_xor(pr, 8);
        if (l15 == 0) yred[g8][wv] = pr;
        __syncthreads();
        if (tid < 4) {
            float s = b_cls[0];
            #pragma unroll
            for (int ww = 0; ww < 16; ++ww) s += yred[tid][ww];
            yout[blk*4 + tid]   = s;
            yscore[blk*4 + tid] = 1.f/(1.f+__expf(-s));
        }
    }
}

// ---------------------------------------------------------------- loss stage 1: per-t
__global__ __launch_bounds__(256) void k_loss_t(
    const float* __restrict__ numpart, const float* __restrict__ denpart,
    float* __restrict__ tpart)
{
    int t = blockIdx.x, tid = threadIdx.x;
    float n = numpart[t*NB2 + tid];
    float d = denpart[t*NB2 + tid];
    for (int off = 32; off; off >>= 1) { n += __shfl_down(n, off); d += __shfl_down(d, off); }
    __shared__ float sn[4], sd[4];
    int lane = tid & 63, wid = tid >> 6;
    if (lane == 0) { sn[wid] = n; sd[wid] = d; }
    __syncthreads();
    if (tid == 0) {
        float nn = sn[0]+sn[1]+sn[2]+sn[3], dd = sd[0]+sd[1]+sd[2]+sd[3];
        tpart[t] = nn / (dd + 1e-5f);
    }
}

// ---------------------------------------------------------------- loss stage 2
__global__ __launch_bounds__(128) void k_loss_final(
    const float* __restrict__ tpart, float* __restrict__ out_loss)
{
    int tid = threadIdx.x;
    float s = tpart[tid];
    for (int off = 32; off; off >>= 1) s += __shfl_down(s, off);
    __shared__ float sp[2];
    if ((tid&63)==0) sp[tid>>6] = s;
    __syncthreads();
    if (tid==0) out_loss[0] = sp[0] + sp[1];
}

static inline size_t al256(size_t x){ return (x + 255) & ~(size_t)255; }

extern "C" void kernel_launch(void* const* d_in, const int* in_sizes, int n_in,
                              void* d_out, int out_size, void* d_ws, size_t ws_size,
                              hipStream_t stream)
{
    const float* x      = (const float*)d_in[0];
    const float* mask   = (const float*)d_in[1];
    const float* deltas = (const float*)d_in[2];
    const float* meanset= (const float*)d_in[3];
    const float* W_h    = (const float*)d_in[4];
    const float* b_h    = (const float*)d_in[5];
    const float* W_x    = (const float*)d_in[6];
    const float* b_x    = (const float*)d_in[7];
    const float* W_ih   = (const float*)d_in[8];
    const float* b_ih   = (const float*)d_in[9];
    const float* W_hh   = (const float*)d_in[10];
    const float* b_hh   = (const float*)d_in[11];
    const float* W_cls  = (const float*)d_in[12];
    const float* b_cls  = (const float*)d_in[13];

    float* out    = (float*)d_out;
    float* ximp   = out;                        // B*T*V
    float* xloss  = out + (size_t)B_*T_*V_;     // 1
    float* yout   = xloss + 1;                  // B
    float* yscore = yout + B_;                  // B

    size_t off = 0;
    size_t off_whh8 = off; off = al256(off + (size_t)H3_*H_);       // fp8
    size_t off_whib = off; off = al256(off + (size_t)H3_*192*2);    // bf16 padded
    size_t off_whp  = off; off = al256(off + (size_t)H_*96*2);      // bf16 padded
    size_t off_np   = off; off = al256(off + (size_t)T_*NB2*4);
    size_t off_dp   = off; off = al256(off + (size_t)T_*NB2*4);
    size_t off_tp   = off; off = al256(off + (size_t)T_*4);
    if (off > ws_size) return;

    char* ws = (char*)d_ws;
    unsigned char* whh8 = (unsigned char*)(ws + off_whh8);
    short* whib   = (short*)(ws + off_whib);
    short* whp    = (short*)(ws + off_whp);
    float* numpart= (float*)(ws + off_np);
    float* denpart= (float*)(ws + off_dp);
    float* tpart  = (float*)(ws + off_tp);

    hipLaunchKernelGGL(k_cvt_fp8, dim3((H3_*H_/4+255)/256), dim3(256), 0, stream, W_hh, whh8, H3_*H_);
    hipLaunchKernelGGL(k_pad_cvt, dim3((H3_*192+255)/256), dim3(256), 0, stream, W_ih, whib, H3_, V2_, 192);
    hipLaunchKernelGGL(k_pad_cvt, dim3((H_*96  +255)/256), dim3(256), 0, stream, W_h,  whp,  H_,  V_,  96);
    hipLaunchKernelGGL(k_fused, dim3(NB2), dim3(1024), 0, stream,
                       x, mask, deltas, meanset, W_x, b_x,
                       whib, whp, whh8, b_ih, b_h, b_hh, W_cls, b_cls,
                       ximp, numpart, denpart, yout, yscore);
    hipLaunchKernelGGL(k_loss_t, dim3(T_), dim3(256), 0, stream, numpart, denpart, tpart);
    hipLaunchKernelGGL(k_loss_final, dim3(1), dim3(128), 0, stream, tpart, xloss);
}

// Round 8
// 327.197 us; speedup vs baseline: 16.7188x; 1.8485x over previous
//
#include <hip/hip_runtime.h>

#define B_  1024
#define T_  128
#define V_  89
#define H_  256
#define NB2 256          // fused-kernel blocks
#define PT_ 4            // timesteps per phase
#define NPH 32           // phases

typedef __attribute__((ext_vector_type(8))) short bf16x8;
typedef __attribute__((ext_vector_type(4))) float f32x4;
typedef __attribute__((ext_vector_type(4))) unsigned short u16x4;

__device__ __forceinline__ short f2bs(float f){
    unsigned u = __float_as_uint(f);
    unsigned r = (u + 0x7FFFu + ((u>>16)&1u)) >> 16;
    return (short)r;
}
__device__ __forceinline__ float s2f(unsigned short s){
    return __uint_as_float(((unsigned)s) << 16);
}
__device__ __forceinline__ float sig_(float x){ return 1.f/(1.f+__expf(-x)); }
__device__ __forceinline__ float tanh_(float x){ return 2.f/(1.f+__expf(-2.f*x)) - 1.f; }

// ---------------------------------------------------------------- W_hh fp32 -> fp8 [768][256]
__global__ __launch_bounds__(256) void k_cvt_fp8(
    const float* __restrict__ src, unsigned char* __restrict__ dst, int n)
{
    int i = blockIdx.x*256 + threadIdx.x;
    if (i*4 >= n) return;
    float f0 = src[i*4+0], f1 = src[i*4+1], f2 = src[i*4+2], f3 = src[i*4+3];
    int w = __builtin_amdgcn_cvt_pk_fp8_f32(f0, f1, 0, false);
    w     = __builtin_amdgcn_cvt_pk_fp8_f32(f2, f3, w, true);
    ((int*)dst)[i] = w;
}

// ---------------------------------------------------------------- W_ih+b_ih -> fp8 [768][192]
// rows k: 0..177 = W_ih cols, 178 = bias, 179..191 = 0
__global__ __launch_bounds__(256) void k_prep_wih8(
    const float* __restrict__ W_ih, const float* __restrict__ b_ih,
    unsigned char* __restrict__ dst)
{
    int i = blockIdx.x*256 + threadIdx.x;      // dword index over 768*48
    if (i >= 768*48) return;
    int n = i / 48, k4 = (i - n*48)*4;
    float f[4];
    #pragma unroll
    for (int j = 0; j < 4; ++j) {
        int k = k4 + j;
        f[j] = (k < 178) ? W_ih[(size_t)n*178 + k] : (k == 178 ? b_ih[n] : 0.f);
    }
    int w = __builtin_amdgcn_cvt_pk_fp8_f32(f[0], f[1], 0, false);
    w     = __builtin_amdgcn_cvt_pk_fp8_f32(f[2], f[3], w, true);
    ((int*)dst)[i] = w;
}

// ---------------------------------------------------------------- W_h+b_h -> bf16 [256][96]
__global__ __launch_bounds__(256) void k_prep_whp(
    const float* __restrict__ W_h, const float* __restrict__ b_h,
    short* __restrict__ dst)
{
    int i = blockIdx.x*256 + threadIdx.x;
    if (i >= 256*96) return;
    int n = i / 96, k = i - n*96;
    float v = (k < V_) ? W_h[(size_t)n*V_ + k] : (k == V_ ? b_h[n] : 0.f);
    dst[i] = f2bs(v);
}

// ---------------------------------------------------------------- gamma_h producer
// grid (256, 32): x = 4-batch group, y = phase (4 t). Output fragment-native:
// gdv u16x4 idx = (p*1024 + bx*4 + g8)*256 + col ; v[rr] = gamma(b, t=p*4+rr, col)
__global__ __launch_bounds__(256) void k_gammah(
    const float* __restrict__ deltas, const short* __restrict__ whp,
    unsigned short* __restrict__ gdv)
{
    __shared__ short dl2[16*104] __attribute__((aligned(16)));
    int tid = threadIdx.x;
    int bx = blockIdx.x, p = blockIdx.y;
    for (int i = tid; i < 16*96; i += 256) {
        int m = i / 96, k = i - m*96;
        int b = bx*4 + (m>>2), t = p*4 + (m&3);
        float val = 0.f;
        if (k < V_)       val = deltas[((size_t)b*T_ + t)*V_ + k];
        else if (k == V_) val = 1.0f;
        dl2[m*104 + k] = f2bs(val);
    }
    __syncthreads();
    int lane = tid & 63, wv = tid >> 6;
    int l15 = lane & 15, g8 = lane >> 4;
    f32x4 z4 = {0.f,0.f,0.f,0.f};
    f32x4 acc[4];
    #pragma unroll
    for (int nt = 0; nt < 4; ++nt) acc[nt] = z4;
    #pragma unroll
    for (int kt = 0; kt < 3; ++kt) {
        bf16x8 a = *(const bf16x8*)&dl2[l15*104 + kt*32 + g8*8];
        #pragma unroll
        for (int nt = 0; nt < 4; ++nt) {
            int cg = wv*64 + nt*16 + l15;
            bf16x8 bb = *(const bf16x8*)(whp + (size_t)cg*96 + kt*32 + g8*8);
            acc[nt] = __builtin_amdgcn_mfma_f32_16x16x32_bf16(a, bb, acc[nt], 0,0,0);
        }
    }
    #pragma unroll
    for (int nt = 0; nt < 4; ++nt) {
        int cg = wv*64 + nt*16 + l15;
        u16x4 v;
        #pragma unroll
        for (int rr = 0; rr < 4; ++rr)
            v[rr] = (unsigned short)f2bs(__expf(-fmaxf(acc[nt][rr], 0.f)));
        ((u16x4*)gdv)[((size_t)(p*1024 + bx*4 + g8))*256 + cg] = v;
    }
}

// ---------------------------------------------------------------- fused kernel
// 256 blocks x 1024 thr. Lane (wv,l15,g8): owns (batch-row g8, col c=wv*16+l15).
// All weights register-resident: W_ih fp8 (36 VGPR), W_hh fp8 (48 VGPR). Bias folded.
__global__ __launch_bounds__(1024, 4) void k_fused(
    const float* __restrict__ x, const float* __restrict__ mask,
    const float* __restrict__ deltas, const float* __restrict__ meanset,
    const float* __restrict__ W_x, const float* __restrict__ b_x,
    const unsigned char* __restrict__ wihb8, const unsigned char* __restrict__ whh8,
    const unsigned short* __restrict__ gdv, const float* __restrict__ b_hh,
    const float* __restrict__ W_cls, const float* __restrict__ b_cls,
    float* __restrict__ ximp, float* __restrict__ numpart, float* __restrict__ denpart,
    float* __restrict__ yout, float* __restrict__ yscore)
{
    __shared__ unsigned char xl[16*200] __attribute__((aligned(16)));  // fp8 [x_h|m|1|0]
    __shared__ unsigned char hlds[2][4*272] __attribute__((aligned(16)));
    __shared__ float lossn[PT_][360], lossd[PT_][360];
    __shared__ float yred[4][16];

    int tid = threadIdx.x;
    int lane = tid & 63, wv = tid >> 6;
    int l15 = lane & 15, g8 = lane >> 4;
    int blk = blockIdx.x;
    int c = wv*16 + l15;

    // static pads of xl: col 178 = fp8(1.0)=0x38, 179..191 = 0
    for (int i = tid; i < 16*14; i += 1024) {
        int r = i / 14, k = 178 + (i - r*14);
        xl[r*200 + k] = (k == 178) ? 0x38 : 0;
    }

    // owners: one per (row, v)
    bool own = (tid < 4*V_);
    int r_o = tid / V_, v_o = tid - r_o*V_;
    int b_o = blk*4 + r_o;
    float wxd = 0.f, bx = 0.f, mnv = 0.f, last = 0.f;
    if (own) { wxd = W_x[v_o*V_ + v_o]; bx = b_x[v_o]; mnv = meanset[v_o]; }

    // register-resident weights
    long wih[3][6];
    #pragma unroll
    for (int g = 0; g < 3; ++g)
        #pragma unroll
        for (int kt = 0; kt < 6; ++kt)
            wih[g][kt] = *(const long*)(wihb8 + (size_t)(g*H_ + c)*192 + kt*32 + g8*8);
    long wf[3][8];
    #pragma unroll
    for (int g = 0; g < 3; ++g)
        #pragma unroll
        for (int kt = 0; kt < 8; ++kt)
            wf[g][kt] = *(const long*)(whh8 + (size_t)(g*H_ + c)*H_ + kt*32 + g8*8);
    float bhh0 = b_hh[c], bhh1 = b_hh[H_ + c], bhh2 = b_hh[2*H_ + c];

    float h = 0.f;

    for (int p = 0; p < NPH; ++p) {
        // ---- gamma prefetch (fragment-native, coalesced 8B/lane)
        u16x4 gdl = ((const u16x4*)gdv)[((size_t)(p*1024 + blk*4 + g8))*256 + c];

        // ================= stage: impute + ffill + loss + xl tile
        if (own) {
            const float* xb = x      + ((size_t)b_o*T_ + p*PT_)*V_ + v_o;
            const float* mb = mask   + ((size_t)b_o*T_ + p*PT_)*V_ + v_o;
            const float* db = deltas + ((size_t)b_o*T_ + p*PT_)*V_ + v_o;
            float xv[PT_], mv[PT_], dv[PT_];
            #pragma unroll
            for (int lt = 0; lt < PT_; ++lt) {
                xv[lt] = xb[lt*V_]; mv[lt] = mb[lt*V_]; dv[lt] = db[lt*V_];
            }
            #pragma unroll
            for (int lt = 0; lt < PT_; ++lt) {
                float xt = xv[lt], m = mv[lt], d = dv[lt];
                float gx = __expf(-fmaxf(fmaf(d, wxd, bx), 0.f));
                last = (m > 0.f) ? xt : last;
                float xu = gx*last + (1.f-gx)*mnv;
                float xh = m*xt + (1.f-m)*xu;
                ximp[((size_t)b_o*T_ + p*PT_ + lt)*V_ + v_o] = xh;
                int mr = r_o*4 + lt;
                int pk = __builtin_amdgcn_cvt_pk_fp8_f32(xh, m, 0, false);
                xl[mr*200 + v_o]      = (unsigned char)(pk & 0xFF);
                xl[mr*200 + V_ + v_o] = (unsigned char)((pk >> 8) & 0xFF);
                lossn[lt][tid] = fabsf(xt - xu)*m;
                lossd[lt][tid] = m;
            }
        }
        __syncthreads();

        // ---- loss reduce (wave 0)
        if (tid < 64) {
            int lt = tid >> 4, part = tid & 15;
            float n = 0.f, ds = 0.f;
            for (int j = part; j < 4*V_; j += 16) { n += lossn[lt][j]; ds += lossd[lt][j]; }
            n += __shfl_xor(n, 1); ds += __shfl_xor(ds, 1);
            n += __shfl_xor(n, 2); ds += __shfl_xor(ds, 2);
            n += __shfl_xor(n, 4); ds += __shfl_xor(ds, 4);
            n += __shfl_xor(n, 8); ds += __shfl_xor(ds, 8);
            if (part == 0) {
                int t = p*PT_ + lt;
                numpart[t*NB2 + blk] = n;
                denpart[t*NB2 + blk] = ds;
            }
        }

        // ================= gates GEMM: fp8, K=192, bias folded (init 0)
        f32x4 ar = {0.f,0.f,0.f,0.f};
        f32x4 az = {0.f,0.f,0.f,0.f};
        f32x4 an = {0.f,0.f,0.f,0.f};
        #pragma unroll
        for (int kt = 0; kt < 6; ++kt) {
            long a = *(const long*)&xl[l15*200 + kt*32 + g8*8];
            ar = __builtin_amdgcn_mfma_f32_16x16x32_fp8_fp8(a, wih[0][kt], ar, 0,0,0);
            az = __builtin_amdgcn_mfma_f32_16x16x32_fp8_fp8(a, wih[1][kt], az, 0,0,0);
            an = __builtin_amdgcn_mfma_f32_16x16x32_fp8_fp8(a, wih[2][kt], an, 0,0,0);
        }

        // ================= recurrence: 4 steps
        #pragma unroll
        for (int lt = 0; lt < PT_; ++lt) {
            const int cb = lt & 1;
            float hd = h * s2f(gdl[lt]);
            int pk = __builtin_amdgcn_cvt_pk_fp8_f32(hd, hd, 0, false);
            hlds[cb][g8*272 + c] = (unsigned char)(pk & 0xFF);
            __syncthreads();
            f32x4 s0 = {bhh0,bhh0,bhh0,bhh0};
            f32x4 s1 = {bhh1,bhh1,bhh1,bhh1};
            f32x4 s2 = {bhh2,bhh2,bhh2,bhh2};
            #pragma unroll
            for (int kt = 0; kt < 8; ++kt) {
                long a = *(const long*)&hlds[cb][(l15>>2)*272 + kt*32 + g8*8];
                s0 = __builtin_amdgcn_mfma_f32_16x16x32_fp8_fp8(a, wf[0][kt], s0, 0,0,0);
                s1 = __builtin_amdgcn_mfma_f32_16x16x32_fp8_fp8(a, wf[1][kt], s1, 0,0,0);
                s2 = __builtin_amdgcn_mfma_f32_16x16x32_fp8_fp8(a, wf[2][kt], s2, 0,0,0);
            }
            float rg = sig_(ar[lt] + s0[0]);
            float zg = sig_(az[lt] + s1[0]);
            float ng = tanh_(an[lt] + rg*s2[0]);
            h = (1.f - zg)*ng + zg*hd;
        }
    }

    // ================= epilogue
    {
        float pr = h * W_cls[c];
        pr += __shfl_xor(pr, 1);
        pr += __shfl_xor(pr, 2);
        pr += __shfl_xor(pr, 4);
        pr += __shfl_xor(pr, 8);
        if (l15 == 0) yred[g8][wv] = pr;
        __syncthreads();
        if (tid < 4) {
            float s = b_cls[0];
            #pragma unroll
            for (int ww = 0; ww < 16; ++ww) s += yred[tid][ww];
            yout[blk*4 + tid]   = s;
            yscore[blk*4 + tid] = 1.f/(1.f+__expf(-s));
        }
    }
}

// ---------------------------------------------------------------- loss stage 1
__global__ __launch_bounds__(256) void k_loss_t(
    const float* __restrict__ numpart, const float* __restrict__ denpart,
    float* __restrict__ tpart)
{
    int t = blockIdx.x, tid = threadIdx.x;
    float n = numpart[t*NB2 + tid];
    float d = denpart[t*NB2 + tid];
    for (int off = 32; off; off >>= 1) { n += __shfl_down(n, off); d += __shfl_down(d, off); }
    __shared__ float sn[4], sd[4];
    int lane = tid & 63, wid = tid >> 6;
    if (lane == 0) { sn[wid] = n; sd[wid] = d; }
    __syncthreads();
    if (tid == 0) {
        float nn = sn[0]+sn[1]+sn[2]+sn[3], dd = sd[0]+sd[1]+sd[2]+sd[3];
        tpart[t] = nn / (dd + 1e-5f);
    }
}

// ---------------------------------------------------------------- loss stage 2
__global__ __launch_bounds__(128) void k_loss_final(
    const float* __restrict__ tpart, float* __restrict__ out_loss)
{
    int tid = threadIdx.x;
    float s = tpart[tid];
    for (int off = 32; off; off >>= 1) s += __shfl_down(s, off);
    __shared__ float sp[2];
    if ((tid&63)==0) sp[tid>>6] = s;
    __syncthreads();
    if (tid==0) out_loss[0] = sp[0] + sp[1];
}

static inline size_t al256(size_t x){ return (x + 255) & ~(size_t)255; }

extern "C" void kernel_launch(void* const* d_in, const int* in_sizes, int n_in,
                              void* d_out, int out_size, void* d_ws, size_t ws_size,
                              hipStream_t stream)
{
    const float* x      = (const float*)d_in[0];
    const float* mask   = (const float*)d_in[1];
    const float* deltas = (const float*)d_in[2];
    const float* meanset= (const float*)d_in[3];
    const float* W_h    = (const float*)d_in[4];
    const float* b_h    = (const float*)d_in[5];
    const float* W_x    = (const float*)d_in[6];
    const float* b_x    = (const float*)d_in[7];
    const float* W_ih   = (const float*)d_in[8];
    const float* b_ih   = (const float*)d_in[9];
    const float* W_hh   = (const float*)d_in[10];
    const float* b_hh   = (const float*)d_in[11];
    const float* W_cls  = (const float*)d_in[12];
    const float* b_cls  = (const float*)d_in[13];

    float* out    = (float*)d_out;
    float* ximp   = out;                        // B*T*V
    float* xloss  = out + (size_t)B_*T_*V_;     // 1
    float* yout   = xloss + 1;                  // B
    float* yscore = yout + B_;                  // B

    size_t off = 0;
    size_t off_whh8 = off; off = al256(off + (size_t)768*256);      // fp8
    size_t off_wih8 = off; off = al256(off + (size_t)768*192);      // fp8, bias folded
    size_t off_whp  = off; off = al256(off + (size_t)256*96*2);     // bf16, bias folded
    size_t off_gdv  = off; off = al256(off + (size_t)B_*T_*H_*2);   // gamma bf16 frag-native
    size_t off_np   = off; off = al256(off + (size_t)T_*NB2*4);
    size_t off_dp   = off; off = al256(off + (size_t)T_*NB2*4);
    size_t off_tp   = off; off = al256(off + (size_t)T_*4);
    if (off > ws_size) return;

    char* ws = (char*)d_ws;
    unsigned char* whh8 = (unsigned char*)(ws + off_whh8);
    unsigned char* wih8 = (unsigned char*)(ws + off_wih8);
    short* whp    = (short*)(ws + off_whp);
    unsigned short* gdv = (unsigned short*)(ws + off_gdv);
    float* numpart= (float*)(ws + off_np);
    float* denpart= (float*)(ws + off_dp);
    float* tpart  = (float*)(ws + off_tp);

    hipLaunchKernelGGL(k_cvt_fp8, dim3((768*256/4+255)/256), dim3(256), 0, stream, W_hh, whh8, 768*256);
    hipLaunchKernelGGL(k_prep_wih8, dim3((768*48+255)/256), dim3(256), 0, stream, W_ih, b_ih, wih8);
    hipLaunchKernelGGL(k_prep_whp, dim3((256*96+255)/256), dim3(256), 0, stream, W_h, b_h, whp);
    hipLaunchKernelGGL(k_gammah, dim3(256, 32), dim3(256), 0, stream, deltas, whp, gdv);
    hipLaunchKernelGGL(k_fused, dim3(NB2), dim3(1024), 0, stream,
                       x, mask, deltas, meanset, W_x, b_x,
                       wih8, whh8, gdv, b_hh, W_cls, b_cls,
                       ximp, numpart, denpart, yout, yscore);
    hipLaunchKernelGGL(k_loss_t, dim3(T_), dim3(256), 0, stream, numpart, denpart, tpart);
    hipLaunchKernelGGL(k_loss_final, dim3(1), dim3(128), 0, stream, tpart, xloss);
}